// Round 16
// baseline (1101.188 us; speedup 1.0000x reference)
//
#include <hip/hip_runtime.h>
#include <hip/hip_bf16.h>

using bf16 = __hip_bfloat16;
typedef __attribute__((ext_vector_type(8))) short short8;
typedef __attribute__((ext_vector_type(4))) float f32x4;

__device__ __forceinline__ unsigned short f2bf(float f) {
  bf16 h = __float2bfloat16(f);
  return *reinterpret_cast<unsigned short*>(&h);
}
__device__ __forceinline__ float bf2f(unsigned short u) {
  return __uint_as_float(((unsigned)u) << 16);
}

__device__ __forceinline__ float loadf(const void* p, int i, int is_f32) {
  if (is_f32) return ((const float*)p)[i];
  return __bfloat162float(((const bf16*)p)[i]);
}

// ---------------------------------------------------------------------------
// init: zero counters + degree-hists + dtype detection (block 0)
// flags[0] = floats are f32, flags[1] = edges are int64
// ---------------------------------------------------------------------------
__global__ __launch_bounds__(256) void init_kernel(
    const int* __restrict__ ei, const unsigned short* __restrict__ x,
    int* __restrict__ flags, int* __restrict__ cnt1, int n1,
    int* __restrict__ cnt2, int n2, int* __restrict__ h1,
    int* __restrict__ h2) {
  int t = threadIdx.x;
  int g = blockIdx.x * 256 + t;
  int stride = gridDim.x * 256;
  for (int i = g; i < n1; i += stride) cnt1[i] = 0;
  for (int i = g; i < n2; i += stride) cnt2[i] = 0;
  if (g < 256) {
    h1[g] = 0;
    h2[g] = 0;
  }
  if (blockIdx.x == 0) {
    __shared__ int red[256];
    int o = 0, big = 0;
    for (int i = t; i < 2048; i += 256) {
      o |= ei[2 * i + 1];
      float v = __uint_as_float(((unsigned)x[2 * i]) << 16);
      if (!(fabsf(v) < 1000.f)) big = 1;
    }
    red[t] = o;
    __syncthreads();
    for (int d = 128; d > 0; d >>= 1) {
      if (t < d) red[t] |= red[t + d];
      __syncthreads();
    }
    int o_all = red[0];
    __syncthreads();
    red[t] = big;
    __syncthreads();
    for (int d = 128; d > 0; d >>= 1) {
      if (t < d) red[t] |= red[t + d];
      __syncthreads();
    }
    if (t == 0) {
      flags[0] = red[0];
      flags[1] = (o_all == 0) ? 1 : 0;
    }
  }
}

__device__ __forceinline__ int edge_src(const int* ei, int E, int e, int i64) {
  return i64 ? ei[2 * e] : ei[e];
}
__device__ __forceinline__ int edge_dst(const int* ei, int E, int e, int i64) {
  return i64 ? ei[2 * E + 2 * e] : ei[E + e];
}

// ---------------------------------------------------------------------------
// node transform: 4 nodes per wave; W/bias/vj in registers.
// ea[n][h] = exp(h . v_j[h]) stored as bf16x8 via 10-shuffle butterfly.
// ---------------------------------------------------------------------------
template <int FIN>
__device__ __forceinline__ void node_body4(
    const void* x, const void* W, const void* b, int is_f32,
    const float* vj, bf16* h_out, unsigned short* ea_out, int n0, int N) {
  int lane = threadIdx.x & 63;
  float wreg[FIN];
#pragma unroll
  for (int f = 0; f < FIN; ++f) wreg[f] = loadf(W, lane * FIN + f, is_f32);
  float bias = loadf(b, lane, is_f32);
  float vjreg[8];
  if (ea_out) {
#pragma unroll
    for (int h = 0; h < 8; ++h) vjreg[h] = vj[h * 64 + lane];
  }
#pragma unroll
  for (int j = 0; j < 4; ++j) {
    int n = n0 + j;
    if (n >= N) break;  // wave-uniform
    float acc = bias;
#pragma unroll
    for (int f = 0; f < FIN; ++f)
      acc += loadf(x, n * FIN + f, is_f32) * wreg[f];
    float hv = acc > 0.f ? acc : expm1f(acc);
    h_out[(unsigned)(n << 6) + lane] = __float2bfloat16(hv);
    if (ea_out) {
      float p[8];
#pragma unroll
      for (int h = 0; h < 8; ++h) p[h] = hv * vjreg[h];
#pragma unroll
      for (int i = 0; i < 4; ++i) {
        float send = (lane & 4) ? p[i] : p[i + 4];
        float keep = (lane & 4) ? p[i + 4] : p[i];
        p[i] = keep + __shfl_xor(send, 4, 64);
      }
#pragma unroll
      for (int i = 0; i < 2; ++i) {
        float send = (lane & 2) ? p[i] : p[i + 2];
        float keep = (lane & 2) ? p[i + 2] : p[i];
        p[i] = keep + __shfl_xor(send, 2, 64);
      }
      {
        float send = (lane & 1) ? p[0] : p[1];
        float keep = (lane & 1) ? p[1] : p[0];
        p[0] = keep + __shfl_xor(send, 1, 64);
      }
      p[0] += __shfl_xor(p[0], 8, 64);
      p[0] += __shfl_xor(p[0], 16, 64);
      p[0] += __shfl_xor(p[0], 32, 64);
      if (lane < 8) ea_out[(unsigned)(n << 3) + lane] = f2bf(__expf(p[0]));
    }
  }
}

// ---------------------------------------------------------------------------
// front: node(op) | node(mc) | prep(weights) | count(edges) in ONE launch
// ---------------------------------------------------------------------------
__global__ __launch_bounds__(256) void front_kernel(
    const void* __restrict__ x_op, const void* __restrict__ W_op,
    const void* __restrict__ b_op, const void* __restrict__ x_mc,
    const void* __restrict__ W_mc, const void* __restrict__ b_mc,
    const void* __restrict__ W1, const void* __restrict__ att1,
    const void* __restrict__ W2, const void* __restrict__ att2,
    const int* __restrict__ ei, const int* __restrict__ flags,
    float* __restrict__ vj1, bf16* __restrict__ Wrt1, float* __restrict__ vj2,
    bf16* __restrict__ Wrt2, bf16* __restrict__ h_op,
    unsigned short* __restrict__ ea_op, bf16* __restrict__ h_mc,
    int* __restrict__ cnt_dst, int* __restrict__ cnt_src, int n_op, int n_mc,
    int E, int nbo, int nbm) {
  int bid = blockIdx.x;
  int is_f32 = flags[0];
  if (bid < nbo) {
    int n0 = bid * 16 + (threadIdx.x >> 6) * 4;
    if (n0 < n_op)
      node_body4<4>(x_op, W_op, b_op, is_f32, vj1, h_op, ea_op, n0, n_op);
  } else if (bid < nbo + nbm) {
    int n0 = (bid - nbo) * 16 + (threadIdx.x >> 6) * 4;
    if (n0 < n_mc)
      node_body4<2>(x_mc, W_mc, b_mc, is_f32, nullptr, h_mc, nullptr, n0, n_mc);
  } else if (bid < nbo + nbm + 256) {
    int pb = bid - nbo - nbm;
    int side = pb >= 128;
    const void* W = side ? W2 : W1;
    const void* att = side ? att2 : att1;
    float* vj = side ? vj2 : vj1;
    bf16* Wrt = side ? Wrt2 : Wrt1;
    int tt = (pb & 127) * 256 + threadIdx.x;
    if (tt < 32768) {
      int c = tt >> 9, k = tt & 511;
      int f = k >> 3, h = k & 7;
      Wrt[tt] = __float2bfloat16(loadf(W, ((h << 6) + c) * 64 + f, is_f32));
    }
    if (tt < 512) {
      int hh = tt >> 6, ff = tt & 63;
      float s = 0.f;
      for (int cc = 0; cc < 64; ++cc)
        s += loadf(att, hh * 128 + 64 + cc, is_f32) *
             loadf(W, ((hh << 6) + cc) * 64 + ff, is_f32);
      vj[tt] = s;
    }
  } else {
    int i64 = flags[1];
    int e = (bid - nbo - nbm - 256) * 256 + threadIdx.x;
    if (e < E) {
      atomicAdd(&cnt_dst[edge_dst(ei, E, e, i64)], 1);
      atomicAdd(&cnt_src[edge_src(ei, E, e, i64)], 1);
    }
  }
}

// ---------------------------------------------------------------------------
// degree-sort machinery: hist -> scan(256 bins) -> scatter (counting sort)
// ---------------------------------------------------------------------------
__global__ __launch_bounds__(256) void hist2_kernel(
    const int* __restrict__ cnt1, int n1, int nbA,
    const int* __restrict__ cnt2, int n2, int* __restrict__ h1,
    int* __restrict__ h2) {
  int side = (int)blockIdx.x >= nbA;
  const int* cnt = side ? cnt2 : cnt1;
  int* h = side ? h2 : h1;
  int n = side ? n2 : n1;
  int blk = side ? (blockIdx.x - nbA) : blockIdx.x;
  int i = blk * 256 + threadIdx.x;
  if (i < n) atomicAdd(&h[min(cnt[i], 255)], 1);
}

__global__ __launch_bounds__(256) void hist_scan(
    const int* __restrict__ h1, int* __restrict__ hc1,
    const int* __restrict__ h2, int* __restrict__ hc2) {
  __shared__ int red[256];
  int t = threadIdx.x;
  // side 1
  red[t] = h1[t];
  __syncthreads();
  for (int d = 1; d < 256; d <<= 1) {
    int v = red[t];
    int add = (t >= d) ? red[t - d] : 0;
    __syncthreads();
    red[t] = v + add;
    __syncthreads();
  }
  hc1[t] = red[t] - h1[t];  // exclusive
  __syncthreads();
  // side 2
  red[t] = h2[t];
  __syncthreads();
  for (int d = 1; d < 256; d <<= 1) {
    int v = red[t];
    int add = (t >= d) ? red[t - d] : 0;
    __syncthreads();
    red[t] = v + add;
    __syncthreads();
  }
  hc2[t] = red[t] - h2[t];
}

__global__ __launch_bounds__(256) void scatter2_kernel(
    const int* __restrict__ cnt1, int n1, int nbA, int* __restrict__ hc1,
    int* __restrict__ perm1, int* __restrict__ inv1, int* __restrict__ cntP1,
    const int* __restrict__ cnt2, int n2, int* __restrict__ hc2,
    int* __restrict__ perm2, int* __restrict__ inv2, int* __restrict__ cntP2) {
  int side = (int)blockIdx.x >= nbA;
  const int* cnt = side ? cnt2 : cnt1;
  int* hc = side ? hc2 : hc1;
  int* perm = side ? perm2 : perm1;
  int* inv = side ? inv2 : inv1;
  int* cntP = side ? cntP2 : cntP1;
  int n = side ? n2 : n1;
  int blk = side ? (blockIdx.x - nbA) : blockIdx.x;
  int i = blk * 256 + threadIdx.x;
  if (i < n) {
    int c = cnt[i];
    int pos = atomicAdd(&hc[min(c, 255)], 1);
    perm[pos] = i;
    inv[i] = pos;
    cntP[pos] = c;
  }
}

// ---------------------------------------------------------------------------
// CSR scan (2 kernels, over PERMUTED counts) + fill (via inv)
// ---------------------------------------------------------------------------
__global__ __launch_bounds__(256) void scan_bsum2(
    const int* __restrict__ cnt1, int n1, int nb1, const int* __restrict__ cnt2,
    int n2, int* __restrict__ bsum1, int* __restrict__ bsum2) {
  __shared__ int red[256];
  int t = threadIdx.x;
  int side = (int)blockIdx.x >= nb1;
  const int* cnt = side ? cnt2 : cnt1;
  int n = side ? n2 : n1;
  int blk = side ? (blockIdx.x - nb1) : blockIdx.x;
  int base = blk * 2048 + t * 8;
  int s = 0;
#pragma unroll
  for (int i = 0; i < 8; ++i)
    if (base + i < n) s += cnt[base + i];
  red[t] = s;
  __syncthreads();
  for (int d = 128; d > 0; d >>= 1) {
    if (t < d) red[t] += red[t + d];
    __syncthreads();
  }
  if (t == 0) (side ? bsum2 : bsum1)[blk] = red[0];
}

__global__ __launch_bounds__(256) void scan_write2(
    const int* __restrict__ cnt1, int n1, int nb1,
    const int* __restrict__ bsum1, int* __restrict__ offs1,
    int* __restrict__ cur1, const int* __restrict__ cnt2, int n2, int nb2,
    const int* __restrict__ bsum2, int* __restrict__ offs2,
    int* __restrict__ cur2) {
  __shared__ int red[256];
  __shared__ int base_s;
  int t = threadIdx.x;
  int side = (int)blockIdx.x >= nb1;
  const int* cnt = side ? cnt2 : cnt1;
  const int* bsum = side ? bsum2 : bsum1;
  int* offs = side ? offs2 : offs1;
  int* cur = side ? cur2 : cur1;
  int n = side ? n2 : n1;
  int nb = side ? nb2 : nb1;
  int blk = side ? (blockIdx.x - nb1) : blockIdx.x;
  if (t == 0) {
    int b = 0;
    for (int i = 0; i < blk; ++i) b += bsum[i];
    base_s = b;
  }
  int base = blk * 2048 + t * 8;
  int c[8];
  int s = 0;
#pragma unroll
  for (int i = 0; i < 8; ++i) {
    c[i] = (base + i < n) ? cnt[base + i] : 0;
    s += c[i];
  }
  red[t] = s;
  __syncthreads();
  for (int d = 1; d < 256; d <<= 1) {
    int v = red[t];
    int add = (t >= d) ? red[t - d] : 0;
    __syncthreads();
    red[t] = v + add;
    __syncthreads();
  }
  int run = base_s + red[t] - s;
#pragma unroll
  for (int i = 0; i < 8; ++i) {
    if (base + i < n) {
      offs[base + i] = run;
      cur[base + i] = run;
      run += c[i];
    }
  }
  if (blk == nb - 1 && t == 255) offs[n] = base_s + red[255];
}

__global__ __launch_bounds__(256) void fill_edges(
    const int* __restrict__ ei, int E, const int* __restrict__ flags,
    const int* __restrict__ inv1, int* __restrict__ cur1,
    int* __restrict__ srcs1, const int* __restrict__ inv2,
    int* __restrict__ cur2, int* __restrict__ srcs2) {
  int i64 = flags[1];
  int e = blockIdx.x * blockDim.x + threadIdx.x;
  if (e < E) {
    int s = edge_src(ei, E, e, i64), d = edge_dst(ei, E, e, i64);
    int p = atomicAdd(&cur1[inv1[d]], 1);
    srcs1[p] = s;
    int q = atomicAdd(&cur2[inv2[s]], 1);
    srcs2[q] = d;
  }
}

// ---------------------------------------------------------------------------
// fused GAT v10: R15 body + DEGREE-SORTED slots. CSR is over sorted slots
// (equal-degree dsts adjacent -> rmax == nj, ~no wasted gather rounds);
// perm[] maps slot -> true dst id at the I/O points only.
// ---------------------------------------------------------------------------
template <bool WRITE_AJ, bool WRITE_BF>
__global__ __launch_bounds__(256) void gat_fused(
    int Nd, const int* __restrict__ offs, const int* __restrict__ srcs,
    const int* __restrict__ perm, const unsigned short* __restrict__ ea,
    const bf16* __restrict__ h_src, const bf16* __restrict__ Wrt,
    const bf16* __restrict__ h_res, float* __restrict__ out_f32,
    bf16* __restrict__ out_bf, const float* __restrict__ vj_next,
    unsigned short* __restrict__ ea_next) {
  __shared__ __align__(16) unsigned short Zl[16 * 520];  // 16.3 KB
  __shared__ float ajp[4][16][8];                        // 2 KB

  int t = threadIdx.x;
  int wv = t >> 6, lane = t & 63;
  int sj = lane >> 4;  // dst slot within wave
  int fq = lane & 15;  // feature quad
  int arow = lane & 15;
  int kg = lane >> 4;
  int col = wv * 16 + arow;

  const unsigned short* hsrc_u = (const unsigned short*)h_src;
  int ntiles = (Nd + 15) >> 4;

  for (int tile = blockIdx.x; tile < ntiles; tile += gridDim.x) {
    int d0 = tile << 4;
    int dlo = d0 + wv * 4;
    int wo0 = offs[min(dlo + 0, Nd)];
    int wo1 = offs[min(dlo + 1, Nd)];
    int wo2 = offs[min(dlo + 2, Nd)];
    int wo3 = offs[min(dlo + 3, Nd)];
    int wo4 = offs[min(dlo + 4, Nd)];
    int woj = sj == 0 ? wo0 : sj == 1 ? wo1 : sj == 2 ? wo2 : wo3;
    int woj1 = sj == 0 ? wo1 : sj == 1 ? wo2 : sj == 2 ? wo3 : wo4;
    int nj = woj1 - woj;

    // true dst ids for this thread's 4 output rows (I/O only)
    int dd[4];
#pragma unroll
    for (int r = 0; r < 4; ++r) {
      int d = d0 + kg * 4 + r;
      dd[r] = (d < Nd) ? perm[d] : 0;
    }

    float z[8][4];
#pragma unroll
    for (int h = 0; h < 8; ++h)
#pragma unroll
      for (int f = 0; f < 4; ++f) z[h][f] = 0.f;
    float s8[8];
#pragma unroll
    for (int h = 0; h < 8; ++h) s8[h] = 0.f;

    int rmax = max(nj, __shfl_xor(nj, 16, 64));
    rmax = max(rmax, __shfl_xor(rmax, 32, 64));

    for (int r0 = 0; r0 < rmax; r0 += 4) {
      unsigned srcq[4];
#pragma unroll
      for (int q = 0; q < 4; ++q) {
        int r = r0 + q;
        srcq[q] = (r < nj) ? (unsigned)srcs[woj + r] : 0u;
      }
      ushort4 uq[4];
      short8 eq[4];
#pragma unroll
      for (int q = 0; q < 4; ++q) {
        unsigned s = srcq[q];
        uq[q] = *(const ushort4*)(hsrc_u + (s << 6) + (fq << 2));
        eq[q] = *(const short8*)(ea + (s << 3));
      }
#pragma unroll
      for (int q = 0; q < 4; ++q) {
        bool act = (r0 + q) < nj;
        float w[8];
#pragma unroll
        for (int h = 0; h < 8; ++h)
          w[h] = act ? bf2f((unsigned short)eq[q][h]) : 0.f;
        float x0 = bf2f(uq[q].x), x1 = bf2f(uq[q].y);
        float x2 = bf2f(uq[q].z), x3 = bf2f(uq[q].w);
#pragma unroll
        for (int h = 0; h < 8; ++h) {
          z[h][0] += w[h] * x0;
          z[h][1] += w[h] * x1;
          z[h][2] += w[h] * x2;
          z[h][3] += w[h] * x3;
          s8[h] += w[h];
        }
      }
    }

    // normalize at pack time -> Zl bf16, row = wv*4+sj, k' = (fq*4+fi)*8+h
    float si[8];
#pragma unroll
    for (int h = 0; h < 8; ++h) si[h] = s8[h] > 0.f ? 1.f / s8[h] : 0.f;
    int row = wv * 4 + sj;
#pragma unroll
    for (int fi = 0; fi < 4; ++fi) {
      int4 pk;
      pk.x = ((int)f2bf(z[1][fi] * si[1]) << 16) | f2bf(z[0][fi] * si[0]);
      pk.y = ((int)f2bf(z[3][fi] * si[3]) << 16) | f2bf(z[2][fi] * si[2]);
      pk.z = ((int)f2bf(z[5][fi] * si[5]) << 16) | f2bf(z[4][fi] * si[4]);
      pk.w = ((int)f2bf(z[7][fi] * si[7]) << 16) | f2bf(z[6][fi] * si[6]);
      *(int4*)&Zl[row * 520 + (fq * 4 + fi) * 8] = pk;
    }

    // prefetch residual (independent of Zl) before the barrier
    float res[4];
#pragma unroll
    for (int r = 0; r < 4; ++r) {
      int d = d0 + kg * 4 + r;
      res[r] = (d < Nd)
                   ? __bfloat162float(h_res[(unsigned)(dd[r] << 6) + col])
                   : 0.f;
    }
    __syncthreads();

    // MFMA epilogue: wave wv computes rows 0..15, cols wv*16..wv*16+15
    f32x4 acc = {0.f, 0.f, 0.f, 0.f};
#pragma unroll
    for (int kt = 0; kt < 16; ++kt) {
      int kbase = kt * 32 + kg * 8;
      short8 a = *(const short8*)&Zl[arow * 520 + kbase];
      short8 b =
          *(const short8*)&Wrt[(unsigned)((wv * 16 + arow) * 512 + kbase)];
      acc = __builtin_amdgcn_mfma_f32_16x16x32_bf16(a, b, acc, 0, 0, 0);
    }

    float o_r[4];
#pragma unroll
    for (int r = 0; r < 4; ++r) {
      int d = d0 + kg * 4 + r;
      float o = 0.f;
      if (d < Nd) {
        float v = res[r] + 0.125f * acc[r];
        o = v > 0.f ? v : expm1f(v);
        out_f32[(unsigned)(dd[r] << 6) + col] = o;
        if (WRITE_BF)
          out_bf[(unsigned)(dd[r] << 6) + col] = __float2bfloat16(o);
      }
      o_r[r] = o;
    }

    if (WRITE_AJ) {
#pragma unroll
      for (int r = 0; r < 4; ++r) {
        int dloc = kg * 4 + r;
        float p[8];
#pragma unroll
        for (int h = 0; h < 8; ++h) p[h] = o_r[r] * vj_next[h * 64 + col];
#pragma unroll
        for (int i = 0; i < 4; ++i) {
          float send = (arow & 4) ? p[i] : p[i + 4];
          float keep = (arow & 4) ? p[i + 4] : p[i];
          p[i] = keep + __shfl_xor(send, 4, 64);
        }
#pragma unroll
        for (int i = 0; i < 2; ++i) {
          float send = (arow & 2) ? p[i] : p[i + 2];
          float keep = (arow & 2) ? p[i + 2] : p[i];
          p[i] = keep + __shfl_xor(send, 2, 64);
        }
        {
          float send = (arow & 1) ? p[0] : p[1];
          float keep = (arow & 1) ? p[1] : p[0];
          p[0] = keep + __shfl_xor(send, 1, 64);
        }
        p[0] += __shfl_xor(p[0], 8, 64);
        if (arow < 8) ajp[wv][dloc][arow] = p[0];
      }
      __syncthreads();
      if (t < 128) {
        int dloc = t >> 3, h = t & 7;
        int d = d0 + dloc;
        if (d < Nd) {
          float s = ajp[0][dloc][h] + ajp[1][dloc][h] + ajp[2][dloc][h] +
                    ajp[3][dloc][h];
          int dtrue = perm[d];
          ea_next[(unsigned)(dtrue << 3) + h] = f2bf(__expf(s));
        }
      }
    }
    __syncthreads();  // protect Zl/ajp reuse across tile iterations
  }
}

// ---------------------------------------------------------------------------
extern "C" void kernel_launch(void* const* d_in, const int* in_sizes, int n_in,
                              void* d_out, int out_size, void* d_ws,
                              size_t ws_size, hipStream_t stream) {
  const void* op_nodes = d_in[0];
  const void* mc_nodes = d_in[1];
  const int* ei        = (const int*)d_in[2];
  const void* W_op     = d_in[3];
  const void* b_op     = d_in[4];
  const void* W_mc     = d_in[5];
  const void* b_mc     = d_in[6];
  const void* W_om     = d_in[7];
  const void* att_om   = d_in[8];
  const void* W_mo     = d_in[9];
  const void* att_mo   = d_in[10];

  int n_op = in_sizes[0] / 4;
  int n_mc = in_sizes[1] / 2;
  int E    = in_sizes[2] / 2;

  char* ws = (char*)d_ws;
  size_t off = 0;
  auto alloc = [&](size_t bytes) -> void* {
    void* p = ws + off;
    off = (off + bytes + 255) & ~(size_t)255;
    return p;
  };
  int* flags   = (int*)alloc(16);
  bf16* h_op   = (bf16*)alloc((size_t)n_op * 64 * 2);
  bf16* h_mc   = (bf16*)alloc((size_t)n_mc * 64 * 2);
  bf16* h_mc2  = (bf16*)alloc((size_t)n_mc * 64 * 2);
  unsigned short* ea_op = (unsigned short*)alloc((size_t)n_op * 8 * 2);
  unsigned short* ea_mc = (unsigned short*)alloc((size_t)n_mc * 8 * 2);
  float* vj_om = (float*)alloc(512 * 4);
  float* vj_mo = (float*)alloc(512 * 4);
  bf16* Wrt_om = (bf16*)alloc(32768 * 2);
  bf16* Wrt_mo = (bf16*)alloc(32768 * 2);
  int* cnt1  = (int*)alloc((size_t)n_mc * 4);
  int* cnt2  = (int*)alloc((size_t)n_op * 4);
  int* offs1 = (int*)alloc((size_t)(n_mc + 1) * 4);
  int* cur1  = (int*)alloc((size_t)n_mc * 4);
  int* srcs1 = (int*)alloc((size_t)E * 4);
  int* offs2 = (int*)alloc((size_t)(n_op + 1) * 4);
  int* cur2  = (int*)alloc((size_t)n_op * 4);
  int* srcs2 = (int*)alloc((size_t)E * 4);
  int* bsum1 = (int*)alloc(256 * 4);
  int* bsum2 = (int*)alloc(256 * 4);
  int* hist1 = (int*)alloc(256 * 4);
  int* hist2 = (int*)alloc(256 * 4);
  int* hcur1 = (int*)alloc(256 * 4);
  int* hcur2 = (int*)alloc(256 * 4);
  int* perm1 = (int*)alloc((size_t)n_mc * 4);
  int* inv1  = (int*)alloc((size_t)n_mc * 4);
  int* cntP1 = (int*)alloc((size_t)n_mc * 4);
  int* perm2 = (int*)alloc((size_t)n_op * 4);
  int* inv2  = (int*)alloc((size_t)n_op * 4);
  int* cntP2 = (int*)alloc((size_t)n_op * 4);

  float* out_op = (float*)d_out;
  float* out_mc = out_op + (size_t)n_op * 64;

  init_kernel<<<512, 256, 0, stream>>>(ei, (const unsigned short*)op_nodes,
                                       flags, cnt1, n_mc, cnt2, n_op, hist1,
                                       hist2);

  int nbo = (n_op + 15) / 16, nbm = (n_mc + 15) / 16;
  int nbe = (E + 255) / 256;
  front_kernel<<<nbo + nbm + 256 + nbe, 256, 0, stream>>>(
      op_nodes, W_op, b_op, mc_nodes, W_mc, b_mc, W_om, att_om, W_mo, att_mo,
      ei, flags, vj_om, Wrt_om, vj_mo, Wrt_mo, h_op, ea_op, h_mc, cnt1, cnt2,
      n_op, n_mc, E, nbo, nbm);

  int nbA = (n_mc + 255) / 256, nbB = (n_op + 255) / 256;
  hist2_kernel<<<nbA + nbB, 256, 0, stream>>>(cnt1, n_mc, nbA, cnt2, n_op,
                                              hist1, hist2);
  hist_scan<<<1, 256, 0, stream>>>(hist1, hcur1, hist2, hcur2);
  scatter2_kernel<<<nbA + nbB, 256, 0, stream>>>(cnt1, n_mc, nbA, hcur1, perm1,
                                                 inv1, cntP1, cnt2, n_op, hcur2,
                                                 perm2, inv2, cntP2);

  int nb1 = (n_mc + 2047) / 2048, nb2 = (n_op + 2047) / 2048;
  scan_bsum2<<<nb1 + nb2, 256, 0, stream>>>(cntP1, n_mc, nb1, cntP2, n_op,
                                            bsum1, bsum2);
  scan_write2<<<nb1 + nb2, 256, 0, stream>>>(cntP1, n_mc, nb1, bsum1, offs1,
                                             cur1, cntP2, n_op, nb2, bsum2,
                                             offs2, cur2);
  fill_edges<<<nbe, 256, 0, stream>>>(ei, E, flags, inv1, cur1, srcs1, inv2,
                                      cur2, srcs2);

  int nt1 = (n_mc + 15) / 16, nt2 = (n_op + 15) / 16;
  // GAT1: op -> mc (writes out_mc f32 + h_mc2 bf16 + ea_mc)
  gat_fused<true, true><<<min(nt1, 2048), 256, 0, stream>>>(
      n_mc, offs1, srcs1, perm1, ea_op, h_op, Wrt_om, h_mc, out_mc, h_mc2,
      vj_mo, ea_mc);
  // GAT2: mc -> op (src = h_mc2 bf16)
  gat_fused<false, false><<<min(nt2, 2048), 256, 0, stream>>>(
      n_op, offs2, srcs2, perm2, ea_mc, h_mc2, Wrt_mo, h_op, out_op,
      (bf16*)nullptr, (const float*)nullptr, (unsigned short*)nullptr);
}

// Round 17
// 235.319 us; speedup vs baseline: 4.6796x; 4.6796x over previous
//
#include <hip/hip_runtime.h>
#include <hip/hip_bf16.h>

using bf16 = __hip_bfloat16;
typedef __attribute__((ext_vector_type(8))) short short8;
typedef __attribute__((ext_vector_type(4))) float f32x4;

__device__ __forceinline__ unsigned short f2bf(float f) {
  bf16 h = __float2bfloat16(f);
  return *reinterpret_cast<unsigned short*>(&h);
}
__device__ __forceinline__ float bf2f(unsigned short u) {
  return __uint_as_float(((unsigned)u) << 16);
}

__device__ __forceinline__ float loadf(const void* p, int i, int is_f32) {
  if (is_f32) return ((const float*)p)[i];
  return __bfloat162float(((const bf16*)p)[i]);
}

// ---------------------------------------------------------------------------
// init: zero counters + degree-hists + dtype detection (block 0)
// ---------------------------------------------------------------------------
__global__ __launch_bounds__(256) void init_kernel(
    const int* __restrict__ ei, const unsigned short* __restrict__ x,
    int* __restrict__ flags, int* __restrict__ cnt1, int n1,
    int* __restrict__ cnt2, int n2, int* __restrict__ h1,
    int* __restrict__ h2) {
  int t = threadIdx.x;
  int g = blockIdx.x * 256 + t;
  int stride = gridDim.x * 256;
  for (int i = g; i < n1; i += stride) cnt1[i] = 0;
  for (int i = g; i < n2; i += stride) cnt2[i] = 0;
  if (g < 256) {
    h1[g] = 0;
    h2[g] = 0;
  }
  if (blockIdx.x == 0) {
    __shared__ int red[256];
    int o = 0, big = 0;
    for (int i = t; i < 2048; i += 256) {
      o |= ei[2 * i + 1];
      float v = __uint_as_float(((unsigned)x[2 * i]) << 16);
      if (!(fabsf(v) < 1000.f)) big = 1;
    }
    red[t] = o;
    __syncthreads();
    for (int d = 128; d > 0; d >>= 1) {
      if (t < d) red[t] |= red[t + d];
      __syncthreads();
    }
    int o_all = red[0];
    __syncthreads();
    red[t] = big;
    __syncthreads();
    for (int d = 128; d > 0; d >>= 1) {
      if (t < d) red[t] |= red[t + d];
      __syncthreads();
    }
    if (t == 0) {
      flags[0] = red[0];
      flags[1] = (o_all == 0) ? 1 : 0;
    }
  }
}

__device__ __forceinline__ int edge_src(const int* ei, int E, int e, int i64) {
  return i64 ? ei[2 * e] : ei[e];
}
__device__ __forceinline__ int edge_dst(const int* ei, int E, int e, int i64) {
  return i64 ? ei[2 * E + 2 * e] : ei[E + e];
}

// ---------------------------------------------------------------------------
// node transform: 4 nodes per wave; W/bias/vj in registers.
// ---------------------------------------------------------------------------
template <int FIN>
__device__ __forceinline__ void node_body4(
    const void* x, const void* W, const void* b, int is_f32,
    const float* vj, bf16* h_out, unsigned short* ea_out, int n0, int N) {
  int lane = threadIdx.x & 63;
  float wreg[FIN];
#pragma unroll
  for (int f = 0; f < FIN; ++f) wreg[f] = loadf(W, lane * FIN + f, is_f32);
  float bias = loadf(b, lane, is_f32);
  float vjreg[8];
  if (ea_out) {
#pragma unroll
    for (int h = 0; h < 8; ++h) vjreg[h] = vj[h * 64 + lane];
  }
#pragma unroll
  for (int j = 0; j < 4; ++j) {
    int n = n0 + j;
    if (n >= N) break;  // wave-uniform
    float acc = bias;
#pragma unroll
    for (int f = 0; f < FIN; ++f)
      acc += loadf(x, n * FIN + f, is_f32) * wreg[f];
    float hv = acc > 0.f ? acc : expm1f(acc);
    h_out[(unsigned)(n << 6) + lane] = __float2bfloat16(hv);
    if (ea_out) {
      float p[8];
#pragma unroll
      for (int h = 0; h < 8; ++h) p[h] = hv * vjreg[h];
#pragma unroll
      for (int i = 0; i < 4; ++i) {
        float send = (lane & 4) ? p[i] : p[i + 4];
        float keep = (lane & 4) ? p[i + 4] : p[i];
        p[i] = keep + __shfl_xor(send, 4, 64);
      }
#pragma unroll
      for (int i = 0; i < 2; ++i) {
        float send = (lane & 2) ? p[i] : p[i + 2];
        float keep = (lane & 2) ? p[i + 2] : p[i];
        p[i] = keep + __shfl_xor(send, 2, 64);
      }
      {
        float send = (lane & 1) ? p[0] : p[1];
        float keep = (lane & 1) ? p[1] : p[0];
        p[0] = keep + __shfl_xor(send, 1, 64);
      }
      p[0] += __shfl_xor(p[0], 8, 64);
      p[0] += __shfl_xor(p[0], 16, 64);
      p[0] += __shfl_xor(p[0], 32, 64);
      if (lane < 8) ea_out[(unsigned)(n << 3) + lane] = f2bf(__expf(p[0]));
    }
  }
}

// ---------------------------------------------------------------------------
// front: node(op) | node(mc) | prep(weights) | count(edges) in ONE launch
// ---------------------------------------------------------------------------
__global__ __launch_bounds__(256) void front_kernel(
    const void* __restrict__ x_op, const void* __restrict__ W_op,
    const void* __restrict__ b_op, const void* __restrict__ x_mc,
    const void* __restrict__ W_mc, const void* __restrict__ b_mc,
    const void* __restrict__ W1, const void* __restrict__ att1,
    const void* __restrict__ W2, const void* __restrict__ att2,
    const int* __restrict__ ei, const int* __restrict__ flags,
    float* __restrict__ vj1, bf16* __restrict__ Wrt1, float* __restrict__ vj2,
    bf16* __restrict__ Wrt2, bf16* __restrict__ h_op,
    unsigned short* __restrict__ ea_op, bf16* __restrict__ h_mc,
    int* __restrict__ cnt_dst, int* __restrict__ cnt_src, int n_op, int n_mc,
    int E, int nbo, int nbm) {
  int bid = blockIdx.x;
  int is_f32 = flags[0];
  if (bid < nbo) {
    int n0 = bid * 16 + (threadIdx.x >> 6) * 4;
    if (n0 < n_op)
      node_body4<4>(x_op, W_op, b_op, is_f32, vj1, h_op, ea_op, n0, n_op);
  } else if (bid < nbo + nbm) {
    int n0 = (bid - nbo) * 16 + (threadIdx.x >> 6) * 4;
    if (n0 < n_mc)
      node_body4<2>(x_mc, W_mc, b_mc, is_f32, nullptr, h_mc, nullptr, n0, n_mc);
  } else if (bid < nbo + nbm + 256) {
    int pb = bid - nbo - nbm;
    int side = pb >= 128;
    const void* W = side ? W2 : W1;
    const void* att = side ? att2 : att1;
    float* vj = side ? vj2 : vj1;
    bf16* Wrt = side ? Wrt2 : Wrt1;
    int tt = (pb & 127) * 256 + threadIdx.x;
    if (tt < 32768) {
      int c = tt >> 9, k = tt & 511;
      int f = k >> 3, h = k & 7;
      Wrt[tt] = __float2bfloat16(loadf(W, ((h << 6) + c) * 64 + f, is_f32));
    }
    if (tt < 512) {
      int hh = tt >> 6, ff = tt & 63;
      float s = 0.f;
      for (int cc = 0; cc < 64; ++cc)
        s += loadf(att, hh * 128 + 64 + cc, is_f32) *
             loadf(W, ((hh << 6) + cc) * 64 + ff, is_f32);
      vj[tt] = s;
    }
  } else {
    int i64 = flags[1];
    int e = (bid - nbo - nbm - 256) * 256 + threadIdx.x;
    if (e < E) {
      atomicAdd(&cnt_dst[edge_dst(ei, E, e, i64)], 1);
      atomicAdd(&cnt_src[edge_src(ei, E, e, i64)], 1);
    }
  }
}

// ---------------------------------------------------------------------------
// degree-sort: per-block LDS histograms -> tiny scan -> rank-based scatter
// (global atomics: one per non-empty bin per block, not one per element)
// ---------------------------------------------------------------------------
__global__ __launch_bounds__(256) void hist2_kernel(
    const int* __restrict__ cnt1, int n1, int nbA,
    const int* __restrict__ cnt2, int n2, int* __restrict__ h1,
    int* __restrict__ h2) {
  __shared__ int lh[256];
  int t = threadIdx.x;
  int side = (int)blockIdx.x >= nbA;
  const int* cnt = side ? cnt2 : cnt1;
  int* h = side ? h2 : h1;
  int n = side ? n2 : n1;
  int blk = side ? (blockIdx.x - nbA) : blockIdx.x;
  int i = blk * 256 + t;
  lh[t] = 0;
  __syncthreads();
  if (i < n) atomicAdd(&lh[min(cnt[i], 255)], 1);
  __syncthreads();
  if (lh[t] > 0) atomicAdd(&h[t], lh[t]);
}

__global__ __launch_bounds__(256) void hist_scan(
    const int* __restrict__ h1, int* __restrict__ hc1,
    const int* __restrict__ h2, int* __restrict__ hc2) {
  __shared__ int red[256];
  int t = threadIdx.x;
  red[t] = h1[t];
  __syncthreads();
  for (int d = 1; d < 256; d <<= 1) {
    int v = red[t];
    int add = (t >= d) ? red[t - d] : 0;
    __syncthreads();
    red[t] = v + add;
    __syncthreads();
  }
  hc1[t] = red[t] - h1[t];  // exclusive
  __syncthreads();
  red[t] = h2[t];
  __syncthreads();
  for (int d = 1; d < 256; d <<= 1) {
    int v = red[t];
    int add = (t >= d) ? red[t - d] : 0;
    __syncthreads();
    red[t] = v + add;
    __syncthreads();
  }
  hc2[t] = red[t] - h2[t];
}

__global__ __launch_bounds__(256) void scatter2_kernel(
    const int* __restrict__ cnt1, int n1, int nbA, int* __restrict__ hc1,
    int* __restrict__ perm1, int* __restrict__ inv1, int* __restrict__ cntP1,
    const int* __restrict__ cnt2, int n2, int* __restrict__ hc2,
    int* __restrict__ perm2, int* __restrict__ inv2, int* __restrict__ cntP2) {
  __shared__ int lh[256];
  __shared__ int gbase[256];
  int t = threadIdx.x;
  int side = (int)blockIdx.x >= nbA;
  const int* cnt = side ? cnt2 : cnt1;
  int* hc = side ? hc2 : hc1;
  int* perm = side ? perm2 : perm1;
  int* inv = side ? inv2 : inv1;
  int* cntP = side ? cntP2 : cntP1;
  int n = side ? n2 : n1;
  int blk = side ? (blockIdx.x - nbA) : blockIdx.x;
  int i = blk * 256 + t;
  lh[t] = 0;
  __syncthreads();
  int c = 0, lrank = 0;
  bool valid = i < n;
  if (valid) {
    c = min(cnt[i], 255);
    lrank = atomicAdd(&lh[c], 1);  // LDS: local rank within (block, bin)
  }
  __syncthreads();
  if (lh[t] > 0) gbase[t] = atomicAdd(&hc[t], lh[t]);  // reserve range
  __syncthreads();
  if (valid) {
    int pos = gbase[c] + lrank;
    perm[pos] = i;
    inv[i] = pos;
    cntP[pos] = cnt[i];
  }
}

// ---------------------------------------------------------------------------
// CSR scan (over PERMUTED counts) + fill (via inv)
// ---------------------------------------------------------------------------
__global__ __launch_bounds__(256) void scan_bsum2(
    const int* __restrict__ cnt1, int n1, int nb1, const int* __restrict__ cnt2,
    int n2, int* __restrict__ bsum1, int* __restrict__ bsum2) {
  __shared__ int red[256];
  int t = threadIdx.x;
  int side = (int)blockIdx.x >= nb1;
  const int* cnt = side ? cnt2 : cnt1;
  int n = side ? n2 : n1;
  int blk = side ? (blockIdx.x - nb1) : blockIdx.x;
  int base = blk * 2048 + t * 8;
  int s = 0;
#pragma unroll
  for (int i = 0; i < 8; ++i)
    if (base + i < n) s += cnt[base + i];
  red[t] = s;
  __syncthreads();
  for (int d = 128; d > 0; d >>= 1) {
    if (t < d) red[t] += red[t + d];
    __syncthreads();
  }
  if (t == 0) (side ? bsum2 : bsum1)[blk] = red[0];
}

__global__ __launch_bounds__(256) void scan_write2(
    const int* __restrict__ cnt1, int n1, int nb1,
    const int* __restrict__ bsum1, int* __restrict__ offs1,
    int* __restrict__ cur1, const int* __restrict__ cnt2, int n2, int nb2,
    const int* __restrict__ bsum2, int* __restrict__ offs2,
    int* __restrict__ cur2) {
  __shared__ int red[256];
  __shared__ int base_s;
  int t = threadIdx.x;
  int side = (int)blockIdx.x >= nb1;
  const int* cnt = side ? cnt2 : cnt1;
  const int* bsum = side ? bsum2 : bsum1;
  int* offs = side ? offs2 : offs1;
  int* cur = side ? cur2 : cur1;
  int n = side ? n2 : n1;
  int nb = side ? nb2 : nb1;
  int blk = side ? (blockIdx.x - nb1) : blockIdx.x;
  if (t == 0) {
    int b = 0;
    for (int i = 0; i < blk; ++i) b += bsum[i];
    base_s = b;
  }
  int base = blk * 2048 + t * 8;
  int c[8];
  int s = 0;
#pragma unroll
  for (int i = 0; i < 8; ++i) {
    c[i] = (base + i < n) ? cnt[base + i] : 0;
    s += c[i];
  }
  red[t] = s;
  __syncthreads();
  for (int d = 1; d < 256; d <<= 1) {
    int v = red[t];
    int add = (t >= d) ? red[t - d] : 0;
    __syncthreads();
    red[t] = v + add;
    __syncthreads();
  }
  int run = base_s + red[t] - s;
#pragma unroll
  for (int i = 0; i < 8; ++i) {
    if (base + i < n) {
      offs[base + i] = run;
      cur[base + i] = run;
      run += c[i];
    }
  }
  if (blk == nb - 1 && t == 255) offs[n] = base_s + red[255];
}

__global__ __launch_bounds__(256) void fill_edges(
    const int* __restrict__ ei, int E, const int* __restrict__ flags,
    const int* __restrict__ inv1, int* __restrict__ cur1,
    int* __restrict__ srcs1, const int* __restrict__ inv2,
    int* __restrict__ cur2, int* __restrict__ srcs2) {
  int i64 = flags[1];
  int e = blockIdx.x * blockDim.x + threadIdx.x;
  if (e < E) {
    int s = edge_src(ei, E, e, i64), d = edge_dst(ei, E, e, i64);
    int p = atomicAdd(&cur1[inv1[d]], 1);
    srcs1[p] = s;
    int q = atomicAdd(&cur2[inv2[s]], 1);
    srcs2[q] = d;
  }
}

// ---------------------------------------------------------------------------
// fused GAT v10: R15 body + DEGREE-SORTED slots (perm maps slot -> dst id).
// ---------------------------------------------------------------------------
template <bool WRITE_AJ, bool WRITE_BF>
__global__ __launch_bounds__(256) void gat_fused(
    int Nd, const int* __restrict__ offs, const int* __restrict__ srcs,
    const int* __restrict__ perm, const unsigned short* __restrict__ ea,
    const bf16* __restrict__ h_src, const bf16* __restrict__ Wrt,
    const bf16* __restrict__ h_res, float* __restrict__ out_f32,
    bf16* __restrict__ out_bf, const float* __restrict__ vj_next,
    unsigned short* __restrict__ ea_next) {
  __shared__ __align__(16) unsigned short Zl[16 * 520];  // 16.3 KB
  __shared__ float ajp[4][16][8];                        // 2 KB

  int t = threadIdx.x;
  int wv = t >> 6, lane = t & 63;
  int sj = lane >> 4;  // dst slot within wave
  int fq = lane & 15;  // feature quad
  int arow = lane & 15;
  int kg = lane >> 4;
  int col = wv * 16 + arow;

  const unsigned short* hsrc_u = (const unsigned short*)h_src;
  int ntiles = (Nd + 15) >> 4;

  for (int tile = blockIdx.x; tile < ntiles; tile += gridDim.x) {
    int d0 = tile << 4;
    int dlo = d0 + wv * 4;
    int wo0 = offs[min(dlo + 0, Nd)];
    int wo1 = offs[min(dlo + 1, Nd)];
    int wo2 = offs[min(dlo + 2, Nd)];
    int wo3 = offs[min(dlo + 3, Nd)];
    int wo4 = offs[min(dlo + 4, Nd)];
    int woj = sj == 0 ? wo0 : sj == 1 ? wo1 : sj == 2 ? wo2 : wo3;
    int woj1 = sj == 0 ? wo1 : sj == 1 ? wo2 : sj == 2 ? wo3 : wo4;
    int nj = woj1 - woj;

    int dd[4];
#pragma unroll
    for (int r = 0; r < 4; ++r) {
      int d = d0 + kg * 4 + r;
      dd[r] = (d < Nd) ? perm[d] : 0;
    }

    float z[8][4];
#pragma unroll
    for (int h = 0; h < 8; ++h)
#pragma unroll
      for (int f = 0; f < 4; ++f) z[h][f] = 0.f;
    float s8[8];
#pragma unroll
    for (int h = 0; h < 8; ++h) s8[h] = 0.f;

    int rmax = max(nj, __shfl_xor(nj, 16, 64));
    rmax = max(rmax, __shfl_xor(rmax, 32, 64));

    for (int r0 = 0; r0 < rmax; r0 += 4) {
      unsigned srcq[4];
#pragma unroll
      for (int q = 0; q < 4; ++q) {
        int r = r0 + q;
        srcq[q] = (r < nj) ? (unsigned)srcs[woj + r] : 0u;
      }
      ushort4 uq[4];
      short8 eq[4];
#pragma unroll
      for (int q = 0; q < 4; ++q) {
        unsigned s = srcq[q];
        uq[q] = *(const ushort4*)(hsrc_u + (s << 6) + (fq << 2));
        eq[q] = *(const short8*)(ea + (s << 3));
      }
#pragma unroll
      for (int q = 0; q < 4; ++q) {
        bool act = (r0 + q) < nj;
        float w[8];
#pragma unroll
        for (int h = 0; h < 8; ++h)
          w[h] = act ? bf2f((unsigned short)eq[q][h]) : 0.f;
        float x0 = bf2f(uq[q].x), x1 = bf2f(uq[q].y);
        float x2 = bf2f(uq[q].z), x3 = bf2f(uq[q].w);
#pragma unroll
        for (int h = 0; h < 8; ++h) {
          z[h][0] += w[h] * x0;
          z[h][1] += w[h] * x1;
          z[h][2] += w[h] * x2;
          z[h][3] += w[h] * x3;
          s8[h] += w[h];
        }
      }
    }

    float si[8];
#pragma unroll
    for (int h = 0; h < 8; ++h) si[h] = s8[h] > 0.f ? 1.f / s8[h] : 0.f;
    int row = wv * 4 + sj;
#pragma unroll
    for (int fi = 0; fi < 4; ++fi) {
      int4 pk;
      pk.x = ((int)f2bf(z[1][fi] * si[1]) << 16) | f2bf(z[0][fi] * si[0]);
      pk.y = ((int)f2bf(z[3][fi] * si[3]) << 16) | f2bf(z[2][fi] * si[2]);
      pk.z = ((int)f2bf(z[5][fi] * si[5]) << 16) | f2bf(z[4][fi] * si[4]);
      pk.w = ((int)f2bf(z[7][fi] * si[7]) << 16) | f2bf(z[6][fi] * si[6]);
      *(int4*)&Zl[row * 520 + (fq * 4 + fi) * 8] = pk;
    }

    float res[4];
#pragma unroll
    for (int r = 0; r < 4; ++r) {
      int d = d0 + kg * 4 + r;
      res[r] = (d < Nd)
                   ? __bfloat162float(h_res[(unsigned)(dd[r] << 6) + col])
                   : 0.f;
    }
    __syncthreads();

    f32x4 acc = {0.f, 0.f, 0.f, 0.f};
#pragma unroll
    for (int kt = 0; kt < 16; ++kt) {
      int kbase = kt * 32 + kg * 8;
      short8 a = *(const short8*)&Zl[arow * 520 + kbase];
      short8 b =
          *(const short8*)&Wrt[(unsigned)((wv * 16 + arow) * 512 + kbase)];
      acc = __builtin_amdgcn_mfma_f32_16x16x32_bf16(a, b, acc, 0, 0, 0);
    }

    float o_r[4];
#pragma unroll
    for (int r = 0; r < 4; ++r) {
      int d = d0 + kg * 4 + r;
      float o = 0.f;
      if (d < Nd) {
        float v = res[r] + 0.125f * acc[r];
        o = v > 0.f ? v : expm1f(v);
        out_f32[(unsigned)(dd[r] << 6) + col] = o;
        if (WRITE_BF)
          out_bf[(unsigned)(dd[r] << 6) + col] = __float2bfloat16(o);
      }
      o_r[r] = o;
    }

    if (WRITE_AJ) {
#pragma unroll
      for (int r = 0; r < 4; ++r) {
        int dloc = kg * 4 + r;
        float p[8];
#pragma unroll
        for (int h = 0; h < 8; ++h) p[h] = o_r[r] * vj_next[h * 64 + col];
#pragma unroll
        for (int i = 0; i < 4; ++i) {
          float send = (arow & 4) ? p[i] : p[i + 4];
          float keep = (arow & 4) ? p[i + 4] : p[i];
          p[i] = keep + __shfl_xor(send, 4, 64);
        }
#pragma unroll
        for (int i = 0; i < 2; ++i) {
          float send = (arow & 2) ? p[i] : p[i + 2];
          float keep = (arow & 2) ? p[i + 2] : p[i];
          p[i] = keep + __shfl_xor(send, 2, 64);
        }
        {
          float send = (arow & 1) ? p[0] : p[1];
          float keep = (arow & 1) ? p[1] : p[0];
          p[0] = keep + __shfl_xor(send, 1, 64);
        }
        p[0] += __shfl_xor(p[0], 8, 64);
        if (arow < 8) ajp[wv][dloc][arow] = p[0];
      }
      __syncthreads();
      if (t < 128) {
        int dloc = t >> 3, h = t & 7;
        int d = d0 + dloc;
        if (d < Nd) {
          float s = ajp[0][dloc][h] + ajp[1][dloc][h] + ajp[2][dloc][h] +
                    ajp[3][dloc][h];
          int dtrue = perm[d];
          ea_next[(unsigned)(dtrue << 3) + h] = f2bf(__expf(s));
        }
      }
    }
    __syncthreads();  // protect Zl/ajp reuse across tile iterations
  }
}

// ---------------------------------------------------------------------------
extern "C" void kernel_launch(void* const* d_in, const int* in_sizes, int n_in,
                              void* d_out, int out_size, void* d_ws,
                              size_t ws_size, hipStream_t stream) {
  const void* op_nodes = d_in[0];
  const void* mc_nodes = d_in[1];
  const int* ei        = (const int*)d_in[2];
  const void* W_op     = d_in[3];
  const void* b_op     = d_in[4];
  const void* W_mc     = d_in[5];
  const void* b_mc     = d_in[6];
  const void* W_om     = d_in[7];
  const void* att_om   = d_in[8];
  const void* W_mo     = d_in[9];
  const void* att_mo   = d_in[10];

  int n_op = in_sizes[0] / 4;
  int n_mc = in_sizes[1] / 2;
  int E    = in_sizes[2] / 2;

  char* ws = (char*)d_ws;
  size_t off = 0;
  auto alloc = [&](size_t bytes) -> void* {
    void* p = ws + off;
    off = (off + bytes + 255) & ~(size_t)255;
    return p;
  };
  int* flags   = (int*)alloc(16);
  bf16* h_op   = (bf16*)alloc((size_t)n_op * 64 * 2);
  bf16* h_mc   = (bf16*)alloc((size_t)n_mc * 64 * 2);
  bf16* h_mc2  = (bf16*)alloc((size_t)n_mc * 64 * 2);
  unsigned short* ea_op = (unsigned short*)alloc((size_t)n_op * 8 * 2);
  unsigned short* ea_mc = (unsigned short*)alloc((size_t)n_mc * 8 * 2);
  float* vj_om = (float*)alloc(512 * 4);
  float* vj_mo = (float*)alloc(512 * 4);
  bf16* Wrt_om = (bf16*)alloc(32768 * 2);
  bf16* Wrt_mo = (bf16*)alloc(32768 * 2);
  int* cnt1  = (int*)alloc((size_t)n_mc * 4);
  int* cnt2  = (int*)alloc((size_t)n_op * 4);
  int* offs1 = (int*)alloc((size_t)(n_mc + 1) * 4);
  int* cur1  = (int*)alloc((size_t)n_mc * 4);
  int* srcs1 = (int*)alloc((size_t)E * 4);
  int* offs2 = (int*)alloc((size_t)(n_op + 1) * 4);
  int* cur2  = (int*)alloc((size_t)n_op * 4);
  int* srcs2 = (int*)alloc((size_t)E * 4);
  int* bsum1 = (int*)alloc(256 * 4);
  int* bsum2 = (int*)alloc(256 * 4);
  int* hist1 = (int*)alloc(256 * 4);
  int* hist2 = (int*)alloc(256 * 4);
  int* hcur1 = (int*)alloc(256 * 4);
  int* hcur2 = (int*)alloc(256 * 4);
  int* perm1 = (int*)alloc((size_t)n_mc * 4);
  int* inv1  = (int*)alloc((size_t)n_mc * 4);
  int* cntP1 = (int*)alloc((size_t)n_mc * 4);
  int* perm2 = (int*)alloc((size_t)n_op * 4);
  int* inv2  = (int*)alloc((size_t)n_op * 4);
  int* cntP2 = (int*)alloc((size_t)n_op * 4);

  float* out_op = (float*)d_out;
  float* out_mc = out_op + (size_t)n_op * 64;

  init_kernel<<<512, 256, 0, stream>>>(ei, (const unsigned short*)op_nodes,
                                       flags, cnt1, n_mc, cnt2, n_op, hist1,
                                       hist2);

  int nbo = (n_op + 15) / 16, nbm = (n_mc + 15) / 16;
  int nbe = (E + 255) / 256;
  front_kernel<<<nbo + nbm + 256 + nbe, 256, 0, stream>>>(
      op_nodes, W_op, b_op, mc_nodes, W_mc, b_mc, W_om, att_om, W_mo, att_mo,
      ei, flags, vj_om, Wrt_om, vj_mo, Wrt_mo, h_op, ea_op, h_mc, cnt1, cnt2,
      n_op, n_mc, E, nbo, nbm);

  int nbA = (n_mc + 255) / 256, nbB = (n_op + 255) / 256;
  hist2_kernel<<<nbA + nbB, 256, 0, stream>>>(cnt1, n_mc, nbA, cnt2, n_op,
                                              hist1, hist2);
  hist_scan<<<1, 256, 0, stream>>>(hist1, hcur1, hist2, hcur2);
  scatter2_kernel<<<nbA + nbB, 256, 0, stream>>>(cnt1, n_mc, nbA, hcur1, perm1,
                                                 inv1, cntP1, cnt2, n_op, hcur2,
                                                 perm2, inv2, cntP2);

  int nb1 = (n_mc + 2047) / 2048, nb2 = (n_op + 2047) / 2048;
  scan_bsum2<<<nb1 + nb2, 256, 0, stream>>>(cntP1, n_mc, nb1, cntP2, n_op,
                                            bsum1, bsum2);
  scan_write2<<<nb1 + nb2, 256, 0, stream>>>(cntP1, n_mc, nb1, bsum1, offs1,
                                             cur1, cntP2, n_op, nb2, bsum2,
                                             offs2, cur2);
  fill_edges<<<nbe, 256, 0, stream>>>(ei, E, flags, inv1, cur1, srcs1, inv2,
                                      cur2, srcs2);

  int nt1 = (n_mc + 15) / 16, nt2 = (n_op + 15) / 16;
  // GAT1: op -> mc (writes out_mc f32 + h_mc2 bf16 + ea_mc)
  gat_fused<true, true><<<min(nt1, 2048), 256, 0, stream>>>(
      n_mc, offs1, srcs1, perm1, ea_op, h_op, Wrt_om, h_mc, out_mc, h_mc2,
      vj_mo, ea_mc);
  // GAT2: mc -> op (src = h_mc2 bf16)
  gat_fused<false, false><<<min(nt2, 2048), 256, 0, stream>>>(
      n_op, offs2, srcs2, perm2, ea_mc, h_mc2, Wrt_mo, h_op, out_op,
      (bf16*)nullptr, (const float*)nullptr, (unsigned short*)nullptr);
}

// Round 18
// 214.285 us; speedup vs baseline: 5.1389x; 1.0982x over previous
//
#include <hip/hip_runtime.h>
#include <hip/hip_bf16.h>

using bf16 = __hip_bfloat16;
typedef __attribute__((ext_vector_type(8))) short short8;
typedef __attribute__((ext_vector_type(4))) float f32x4;

__device__ __forceinline__ unsigned short f2bf(float f) {
  bf16 h = __float2bfloat16(f);
  return *reinterpret_cast<unsigned short*>(&h);
}
__device__ __forceinline__ float bf2f(unsigned short u) {
  return __uint_as_float(((unsigned)u) << 16);
}

__device__ __forceinline__ float loadf(const void* p, int i, int is_f32) {
  if (is_f32) return ((const float*)p)[i];
  return __bfloat162float(((const bf16*)p)[i]);
}

// ---------------------------------------------------------------------------
// init: zero counters + dtype detection (block 0)
// flags[0] = floats are f32, flags[1] = edges are int64
// ---------------------------------------------------------------------------
__global__ __launch_bounds__(256) void init_kernel(
    const int* __restrict__ ei, const unsigned short* __restrict__ x,
    int* __restrict__ flags, int* __restrict__ cnt1, int n1,
    int* __restrict__ cnt2, int n2) {
  int t = threadIdx.x;
  int g = blockIdx.x * 256 + t;
  int stride = gridDim.x * 256;
  for (int i = g; i < n1; i += stride) cnt1[i] = 0;
  for (int i = g; i < n2; i += stride) cnt2[i] = 0;
  if (blockIdx.x == 0) {
    __shared__ int red[256];
    int o = 0, big = 0;
    for (int i = t; i < 2048; i += 256) {
      o |= ei[2 * i + 1];
      float v = __uint_as_float(((unsigned)x[2 * i]) << 16);
      if (!(fabsf(v) < 1000.f)) big = 1;
    }
    red[t] = o;
    __syncthreads();
    for (int d = 128; d > 0; d >>= 1) {
      if (t < d) red[t] |= red[t + d];
      __syncthreads();
    }
    int o_all = red[0];
    __syncthreads();
    red[t] = big;
    __syncthreads();
    for (int d = 128; d > 0; d >>= 1) {
      if (t < d) red[t] |= red[t + d];
      __syncthreads();
    }
    if (t == 0) {
      flags[0] = red[0];
      flags[1] = (o_all == 0) ? 1 : 0;
    }
  }
}

__device__ __forceinline__ int edge_src(const int* ei, int E, int e, int i64) {
  return i64 ? ei[2 * e] : ei[e];
}
__device__ __forceinline__ int edge_dst(const int* ei, int E, int e, int i64) {
  return i64 ? ei[2 * E + 2 * e] : ei[E + e];
}

// ---------------------------------------------------------------------------
// node transform: 4 nodes per wave; W/bias/vj in registers.
// ea[n][h] = exp(h . v_j[h]) stored as bf16x8 via 10-shuffle butterfly.
// ---------------------------------------------------------------------------
template <int FIN>
__device__ __forceinline__ void node_body4(
    const void* x, const void* W, const void* b, int is_f32,
    const float* vj, bf16* h_out, unsigned short* ea_out, int n0, int N) {
  int lane = threadIdx.x & 63;
  float wreg[FIN];
#pragma unroll
  for (int f = 0; f < FIN; ++f) wreg[f] = loadf(W, lane * FIN + f, is_f32);
  float bias = loadf(b, lane, is_f32);
  float vjreg[8];
  if (ea_out) {
#pragma unroll
    for (int h = 0; h < 8; ++h) vjreg[h] = vj[h * 64 + lane];
  }
#pragma unroll
  for (int j = 0; j < 4; ++j) {
    int n = n0 + j;
    if (n >= N) break;  // wave-uniform
    float acc = bias;
#pragma unroll
    for (int f = 0; f < FIN; ++f)
      acc += loadf(x, n * FIN + f, is_f32) * wreg[f];
    float hv = acc > 0.f ? acc : expm1f(acc);
    h_out[(unsigned)(n << 6) + lane] = __float2bfloat16(hv);
    if (ea_out) {
      float p[8];
#pragma unroll
      for (int h = 0; h < 8; ++h) p[h] = hv * vjreg[h];
#pragma unroll
      for (int i = 0; i < 4; ++i) {
        float send = (lane & 4) ? p[i] : p[i + 4];
        float keep = (lane & 4) ? p[i + 4] : p[i];
        p[i] = keep + __shfl_xor(send, 4, 64);
      }
#pragma unroll
      for (int i = 0; i < 2; ++i) {
        float send = (lane & 2) ? p[i] : p[i + 2];
        float keep = (lane & 2) ? p[i + 2] : p[i];
        p[i] = keep + __shfl_xor(send, 2, 64);
      }
      {
        float send = (lane & 1) ? p[0] : p[1];
        float keep = (lane & 1) ? p[1] : p[0];
        p[0] = keep + __shfl_xor(send, 1, 64);
      }
      p[0] += __shfl_xor(p[0], 8, 64);
      p[0] += __shfl_xor(p[0], 16, 64);
      p[0] += __shfl_xor(p[0], 32, 64);
      if (lane < 8) ea_out[(unsigned)(n << 3) + lane] = f2bf(__expf(p[0]));
    }
  }
}

// ---------------------------------------------------------------------------
// front: node(op) | node(mc) | prep(weights) | count(edges) in ONE launch
// ---------------------------------------------------------------------------
__global__ __launch_bounds__(256) void front_kernel(
    const void* __restrict__ x_op, const void* __restrict__ W_op,
    const void* __restrict__ b_op, const void* __restrict__ x_mc,
    const void* __restrict__ W_mc, const void* __restrict__ b_mc,
    const void* __restrict__ W1, const void* __restrict__ att1,
    const void* __restrict__ W2, const void* __restrict__ att2,
    const int* __restrict__ ei, const int* __restrict__ flags,
    float* __restrict__ vj1, bf16* __restrict__ Wrt1, float* __restrict__ vj2,
    bf16* __restrict__ Wrt2, bf16* __restrict__ h_op,
    unsigned short* __restrict__ ea_op, bf16* __restrict__ h_mc,
    int* __restrict__ cnt_dst, int* __restrict__ cnt_src, int n_op, int n_mc,
    int E, int nbo, int nbm) {
  int bid = blockIdx.x;
  int is_f32 = flags[0];
  if (bid < nbo) {
    int n0 = bid * 16 + (threadIdx.x >> 6) * 4;
    if (n0 < n_op)
      node_body4<4>(x_op, W_op, b_op, is_f32, vj1, h_op, ea_op, n0, n_op);
  } else if (bid < nbo + nbm) {
    int n0 = (bid - nbo) * 16 + (threadIdx.x >> 6) * 4;
    if (n0 < n_mc)
      node_body4<2>(x_mc, W_mc, b_mc, is_f32, nullptr, h_mc, nullptr, n0, n_mc);
  } else if (bid < nbo + nbm + 256) {
    int pb = bid - nbo - nbm;
    int side = pb >= 128;
    const void* W = side ? W2 : W1;
    const void* att = side ? att2 : att1;
    float* vj = side ? vj2 : vj1;
    bf16* Wrt = side ? Wrt2 : Wrt1;
    int tt = (pb & 127) * 256 + threadIdx.x;
    if (tt < 32768) {
      int c = tt >> 9, k = tt & 511;
      int f = k >> 3, h = k & 7;
      Wrt[tt] = __float2bfloat16(loadf(W, ((h << 6) + c) * 64 + f, is_f32));
    }
    if (tt < 512) {
      int hh = tt >> 6, ff = tt & 63;
      float s = 0.f;
      for (int cc = 0; cc < 64; ++cc)
        s += loadf(att, hh * 128 + 64 + cc, is_f32) *
             loadf(W, ((hh << 6) + cc) * 64 + ff, is_f32);
      vj[tt] = s;
    }
  } else {
    int i64 = flags[1];
    int e = (bid - nbo - nbm - 256) * 256 + threadIdx.x;
    if (e < E) {
      atomicAdd(&cnt_dst[edge_dst(ei, E, e, i64)], 1);
      atomicAdd(&cnt_src[edge_src(ei, E, e, i64)], 1);
    }
  }
}

// ---------------------------------------------------------------------------
// CSR scan (2 kernels) + fill
// ---------------------------------------------------------------------------
__global__ __launch_bounds__(256) void scan_bsum2(
    const int* __restrict__ cnt1, int n1, int nb1, const int* __restrict__ cnt2,
    int n2, int* __restrict__ bsum1, int* __restrict__ bsum2) {
  __shared__ int red[256];
  int t = threadIdx.x;
  int side = (int)blockIdx.x >= nb1;
  const int* cnt = side ? cnt2 : cnt1;
  int n = side ? n2 : n1;
  int blk = side ? (blockIdx.x - nb1) : blockIdx.x;
  int base = blk * 2048 + t * 8;
  int s = 0;
#pragma unroll
  for (int i = 0; i < 8; ++i)
    if (base + i < n) s += cnt[base + i];
  red[t] = s;
  __syncthreads();
  for (int d = 128; d > 0; d >>= 1) {
    if (t < d) red[t] += red[t + d];
    __syncthreads();
  }
  if (t == 0) (side ? bsum2 : bsum1)[blk] = red[0];
}

__global__ __launch_bounds__(256) void scan_write2(
    const int* __restrict__ cnt1, int n1, int nb1,
    const int* __restrict__ bsum1, int* __restrict__ offs1,
    int* __restrict__ cur1, const int* __restrict__ cnt2, int n2, int nb2,
    const int* __restrict__ bsum2, int* __restrict__ offs2,
    int* __restrict__ cur2) {
  __shared__ int red[256];
  __shared__ int base_s;
  int t = threadIdx.x;
  int side = (int)blockIdx.x >= nb1;
  const int* cnt = side ? cnt2 : cnt1;
  const int* bsum = side ? bsum2 : bsum1;
  int* offs = side ? offs2 : offs1;
  int* cur = side ? cur2 : cur1;
  int n = side ? n2 : n1;
  int nb = side ? nb2 : nb1;
  int blk = side ? (blockIdx.x - nb1) : blockIdx.x;
  if (t == 0) {
    int b = 0;
    for (int i = 0; i < blk; ++i) b += bsum[i];
    base_s = b;
  }
  int base = blk * 2048 + t * 8;
  int c[8];
  int s = 0;
#pragma unroll
  for (int i = 0; i < 8; ++i) {
    c[i] = (base + i < n) ? cnt[base + i] : 0;
    s += c[i];
  }
  red[t] = s;
  __syncthreads();
  for (int d = 1; d < 256; d <<= 1) {
    int v = red[t];
    int add = (t >= d) ? red[t - d] : 0;
    __syncthreads();
    red[t] = v + add;
    __syncthreads();
  }
  int run = base_s + red[t] - s;
#pragma unroll
  for (int i = 0; i < 8; ++i) {
    if (base + i < n) {
      offs[base + i] = run;
      cur[base + i] = run;
      run += c[i];
    }
  }
  if (blk == nb - 1 && t == 255) offs[n] = base_s + red[255];
}

__global__ __launch_bounds__(256) void fill_edges(
    const int* __restrict__ ei, int E, const int* __restrict__ flags,
    int* __restrict__ cur1, int* __restrict__ srcs1, int* __restrict__ cur2,
    int* __restrict__ srcs2) {
  int i64 = flags[1];
  int e = blockIdx.x * blockDim.x + threadIdx.x;
  if (e < E) {
    int s = edge_src(ei, E, e, i64), d = edge_dst(ei, E, e, i64);
    int p = atomicAdd(&cur1[d], 1);
    srcs1[p] = s;
    int q = atomicAdd(&cur2[s], 1);
    srcs2[q] = d;
  }
}

// ---------------------------------------------------------------------------
// fused GAT v11: R12 structure (non-persistent, 16 dst/block, zero staging)
// + 2-deep SOFTWARE-PIPELINED quad-rounds: rows/srcs for round i+1 issue
// before round i's fma block, hiding both hops of the srcs->rows->fma chain.
// ---------------------------------------------------------------------------
template <bool WRITE_AJ, bool WRITE_BF>
__global__ __launch_bounds__(256) void gat_fused(
    int Nd, const int* __restrict__ offs, const int* __restrict__ srcs,
    const unsigned short* __restrict__ ea, const bf16* __restrict__ h_src,
    const bf16* __restrict__ Wrt, const bf16* __restrict__ h_res,
    float* __restrict__ out_f32, bf16* __restrict__ out_bf,
    const float* __restrict__ vj_next, unsigned short* __restrict__ ea_next) {
  __shared__ __align__(16) unsigned short Zl[16 * 520];  // 16.3 KB
  __shared__ float ajp[4][16][8];                        // 2 KB

  int t = threadIdx.x;
  int wv = t >> 6, lane = t & 63;
  int sj = lane >> 4;  // dst slot within wave
  int fq = lane & 15;  // feature quad
  int arow = lane & 15;
  int kg = lane >> 4;
  int col = wv * 16 + arow;
  int d0 = blockIdx.x * 16;

  const unsigned short* hsrc_u = (const unsigned short*)h_src;

  int dlo = d0 + wv * 4;
  int wo0 = offs[min(dlo + 0, Nd)];
  int wo1 = offs[min(dlo + 1, Nd)];
  int wo2 = offs[min(dlo + 2, Nd)];
  int wo3 = offs[min(dlo + 3, Nd)];
  int wo4 = offs[min(dlo + 4, Nd)];
  int woj = sj == 0 ? wo0 : sj == 1 ? wo1 : sj == 2 ? wo2 : wo3;
  int woj1 = sj == 0 ? wo1 : sj == 1 ? wo2 : sj == 2 ? wo3 : wo4;
  int nj = woj1 - woj;

  float z[8][4];
#pragma unroll
  for (int h = 0; h < 8; ++h)
#pragma unroll
    for (int f = 0; f < 4; ++f) z[h][f] = 0.f;
  float s8[8];
#pragma unroll
  for (int h = 0; h < 8; ++h) s8[h] = 0.f;

  int rmax = max(nj, __shfl_xor(nj, 16, 64));
  rmax = max(rmax, __shfl_xor(rmax, 32, 64));

  // ---- 2-deep pipelined gather ----
  unsigned srcA[4], srcB[4];
  ushort4 uqA[4];
  short8 eqA[4];
#pragma unroll
  for (int q = 0; q < 4; ++q)
    srcA[q] = (q < nj) ? (unsigned)srcs[woj + q] : 0u;
#pragma unroll
  for (int q = 0; q < 4; ++q) {
    uqA[q] = *(const ushort4*)(hsrc_u + (srcA[q] << 6) + (fq << 2));
    eqA[q] = *(const short8*)(ea + (srcA[q] << 3));
  }
#pragma unroll
  for (int q = 0; q < 4; ++q)
    srcB[q] = (4 + q < nj) ? (unsigned)srcs[woj + 4 + q] : 0u;

  for (int r0 = 0; r0 < rmax; r0 += 4) {
    // issue NEXT round's rows/ea (from srcB) and srcs for round r0+8
    ushort4 uqN[4];
    short8 eqN[4];
    unsigned srcN[4];
#pragma unroll
    for (int q = 0; q < 4; ++q) {
      uqN[q] = *(const ushort4*)(hsrc_u + (srcB[q] << 6) + (fq << 2));
      eqN[q] = *(const short8*)(ea + (srcB[q] << 3));
    }
#pragma unroll
    for (int q = 0; q < 4; ++q) {
      int r = r0 + 8 + q;
      srcN[q] = (r < nj) ? (unsigned)srcs[woj + r] : 0u;
    }
    // compute on CURRENT round (uqA/eqA)
#pragma unroll
    for (int q = 0; q < 4; ++q) {
      bool act = (r0 + q) < nj;
      float w[8];
#pragma unroll
      for (int h = 0; h < 8; ++h)
        w[h] = act ? bf2f((unsigned short)eqA[q][h]) : 0.f;
      float x0 = bf2f(uqA[q].x), x1 = bf2f(uqA[q].y);
      float x2 = bf2f(uqA[q].z), x3 = bf2f(uqA[q].w);
#pragma unroll
      for (int h = 0; h < 8; ++h) {
        z[h][0] += w[h] * x0;
        z[h][1] += w[h] * x1;
        z[h][2] += w[h] * x2;
        z[h][3] += w[h] * x3;
        s8[h] += w[h];
      }
    }
    // rotate pipeline
#pragma unroll
    for (int q = 0; q < 4; ++q) {
      uqA[q] = uqN[q];
      eqA[q] = eqN[q];
      srcB[q] = srcN[q];
    }
  }

  // normalize at pack time -> Zl bf16, row = wv*4+sj, k' = (fq*4+fi)*8 + h
  float si[8];
#pragma unroll
  for (int h = 0; h < 8; ++h) si[h] = s8[h] > 0.f ? 1.f / s8[h] : 0.f;
  int row = wv * 4 + sj;
#pragma unroll
  for (int fi = 0; fi < 4; ++fi) {
    int4 pk;
    pk.x = ((int)f2bf(z[1][fi] * si[1]) << 16) | f2bf(z[0][fi] * si[0]);
    pk.y = ((int)f2bf(z[3][fi] * si[3]) << 16) | f2bf(z[2][fi] * si[2]);
    pk.z = ((int)f2bf(z[5][fi] * si[5]) << 16) | f2bf(z[4][fi] * si[4]);
    pk.w = ((int)f2bf(z[7][fi] * si[7]) << 16) | f2bf(z[6][fi] * si[6]);
    *(int4*)&Zl[row * 520 + (fq * 4 + fi) * 8] = pk;
  }

  // prefetch residual (independent of Zl) before the barrier
  float res[4];
#pragma unroll
  for (int r = 0; r < 4; ++r) {
    int d = d0 + kg * 4 + r;
    res[r] =
        (d < Nd) ? __bfloat162float(h_res[(unsigned)(d << 6) + col]) : 0.f;
  }
  __syncthreads();

  // MFMA epilogue: wave wv computes rows 0..15, cols wv*16..wv*16+15
  f32x4 acc = {0.f, 0.f, 0.f, 0.f};
#pragma unroll
  for (int kt = 0; kt < 16; ++kt) {
    int kbase = kt * 32 + kg * 8;
    short8 a = *(const short8*)&Zl[arow * 520 + kbase];
    short8 b = *(const short8*)&Wrt[(unsigned)((wv * 16 + arow) * 512 + kbase)];
    acc = __builtin_amdgcn_mfma_f32_16x16x32_bf16(a, b, acc, 0, 0, 0);
  }

  float o_r[4];
#pragma unroll
  for (int r = 0; r < 4; ++r) {
    int d = d0 + kg * 4 + r;
    float o = 0.f;
    if (d < Nd) {
      float v = res[r] + 0.125f * acc[r];
      o = v > 0.f ? v : expm1f(v);
      out_f32[(unsigned)(d << 6) + col] = o;
      if (WRITE_BF) out_bf[(unsigned)(d << 6) + col] = __float2bfloat16(o);
    }
    o_r[r] = o;
  }

  if (WRITE_AJ) {
#pragma unroll
    for (int r = 0; r < 4; ++r) {
      int dloc = kg * 4 + r;
      float p[8];
#pragma unroll
      for (int h = 0; h < 8; ++h) p[h] = o_r[r] * vj_next[h * 64 + col];
#pragma unroll
      for (int i = 0; i < 4; ++i) {
        float send = (arow & 4) ? p[i] : p[i + 4];
        float keep = (arow & 4) ? p[i + 4] : p[i];
        p[i] = keep + __shfl_xor(send, 4, 64);
      }
#pragma unroll
      for (int i = 0; i < 2; ++i) {
        float send = (arow & 2) ? p[i] : p[i + 2];
        float keep = (arow & 2) ? p[i + 2] : p[i];
        p[i] = keep + __shfl_xor(send, 2, 64);
      }
      {
        float send = (arow & 1) ? p[0] : p[1];
        float keep = (arow & 1) ? p[1] : p[0];
        p[0] = keep + __shfl_xor(send, 1, 64);
      }
      p[0] += __shfl_xor(p[0], 8, 64);
      if (arow < 8) ajp[wv][dloc][arow] = p[0];
    }
    __syncthreads();
    if (t < 128) {
      int dloc = t >> 3, h = t & 7;
      int d = d0 + dloc;
      if (d < Nd) {
        float s = ajp[0][dloc][h] + ajp[1][dloc][h] + ajp[2][dloc][h] +
                  ajp[3][dloc][h];
        ea_next[(unsigned)(d << 3) + h] = f2bf(__expf(s));
      }
    }
  }
}

// ---------------------------------------------------------------------------
extern "C" void kernel_launch(void* const* d_in, const int* in_sizes, int n_in,
                              void* d_out, int out_size, void* d_ws,
                              size_t ws_size, hipStream_t stream) {
  const void* op_nodes = d_in[0];
  const void* mc_nodes = d_in[1];
  const int* ei        = (const int*)d_in[2];
  const void* W_op     = d_in[3];
  const void* b_op     = d_in[4];
  const void* W_mc     = d_in[5];
  const void* b_mc     = d_in[6];
  const void* W_om     = d_in[7];
  const void* att_om   = d_in[8];
  const void* W_mo     = d_in[9];
  const void* att_mo   = d_in[10];

  int n_op = in_sizes[0] / 4;
  int n_mc = in_sizes[1] / 2;
  int E    = in_sizes[2] / 2;

  char* ws = (char*)d_ws;
  size_t off = 0;
  auto alloc = [&](size_t bytes) -> void* {
    void* p = ws + off;
    off = (off + bytes + 255) & ~(size_t)255;
    return p;
  };
  int* flags   = (int*)alloc(16);
  bf16* h_op   = (bf16*)alloc((size_t)n_op * 64 * 2);
  bf16* h_mc   = (bf16*)alloc((size_t)n_mc * 64 * 2);
  bf16* h_mc2  = (bf16*)alloc((size_t)n_mc * 64 * 2);
  unsigned short* ea_op = (unsigned short*)alloc((size_t)n_op * 8 * 2);
  unsigned short* ea_mc = (unsigned short*)alloc((size_t)n_mc * 8 * 2);
  float* vj_om = (float*)alloc(512 * 4);
  float* vj_mo = (float*)alloc(512 * 4);
  bf16* Wrt_om = (bf16*)alloc(32768 * 2);
  bf16* Wrt_mo = (bf16*)alloc(32768 * 2);
  int* cnt1  = (int*)alloc((size_t)n_mc * 4);
  int* cnt2  = (int*)alloc((size_t)n_op * 4);
  int* offs1 = (int*)alloc((size_t)(n_mc + 1) * 4);
  int* cur1  = (int*)alloc((size_t)n_mc * 4);
  int* srcs1 = (int*)alloc((size_t)E * 4);
  int* offs2 = (int*)alloc((size_t)(n_op + 1) * 4);
  int* cur2  = (int*)alloc((size_t)n_op * 4);
  int* srcs2 = (int*)alloc((size_t)E * 4);
  int* bsum1 = (int*)alloc(256 * 4);
  int* bsum2 = (int*)alloc(256 * 4);

  float* out_op = (float*)d_out;
  float* out_mc = out_op + (size_t)n_op * 64;

  init_kernel<<<512, 256, 0, stream>>>(ei, (const unsigned short*)op_nodes,
                                       flags, cnt1, n_mc, cnt2, n_op);

  int nbo = (n_op + 15) / 16, nbm = (n_mc + 15) / 16;
  int nbe = (E + 255) / 256;
  front_kernel<<<nbo + nbm + 256 + nbe, 256, 0, stream>>>(
      op_nodes, W_op, b_op, mc_nodes, W_mc, b_mc, W_om, att_om, W_mo, att_mo,
      ei, flags, vj_om, Wrt_om, vj_mo, Wrt_mo, h_op, ea_op, h_mc, cnt1, cnt2,
      n_op, n_mc, E, nbo, nbm);

  int nb1 = (n_mc + 2047) / 2048, nb2 = (n_op + 2047) / 2048;
  scan_bsum2<<<nb1 + nb2, 256, 0, stream>>>(cnt1, n_mc, nb1, cnt2, n_op, bsum1,
                                            bsum2);
  scan_write2<<<nb1 + nb2, 256, 0, stream>>>(cnt1, n_mc, nb1, bsum1, offs1,
                                             cur1, cnt2, n_op, nb2, bsum2,
                                             offs2, cur2);
  fill_edges<<<nbe, 256, 0, stream>>>(ei, E, flags, cur1, srcs1, cur2, srcs2);

  // GAT1: op -> mc (writes out_mc f32 + h_mc2 bf16 + ea_mc)
  gat_fused<true, true><<<(n_mc + 15) / 16, 256, 0, stream>>>(
      n_mc, offs1, srcs1, ea_op, h_op, Wrt_om, h_mc, out_mc, h_mc2, vj_mo,
      ea_mc);
  // GAT2: mc -> op (src = h_mc2 bf16)
  gat_fused<false, false><<<(n_op + 15) / 16, 256, 0, stream>>>(
      n_op, offs2, srcs2, ea_mc, h_mc2, Wrt_mo, h_op, out_op, (bf16*)nullptr,
      (const float*)nullptr, (unsigned short*)nullptr);
}

// Round 19
// 206.162 us; speedup vs baseline: 5.3414x; 1.0394x over previous
//
#include <hip/hip_runtime.h>
#include <hip/hip_bf16.h>

using bf16 = __hip_bfloat16;
typedef __attribute__((ext_vector_type(8))) short short8;
typedef __attribute__((ext_vector_type(4))) float f32x4;

__device__ __forceinline__ unsigned short f2bf(float f) {
  bf16 h = __float2bfloat16(f);
  return *reinterpret_cast<unsigned short*>(&h);
}
__device__ __forceinline__ float bf2f(unsigned short u) {
  return __uint_as_float(((unsigned)u) << 16);
}

__device__ __forceinline__ float loadf(const void* p, int i, int is_f32) {
  if (is_f32) return ((const float*)p)[i];
  return __bfloat162float(((const bf16*)p)[i]);
}

// ---------------------------------------------------------------------------
// init: zero counters + dtype detection (block 0)
// flags[0] = floats are f32, flags[1] = edges are int64
// ---------------------------------------------------------------------------
__global__ __launch_bounds__(256) void init_kernel(
    const int* __restrict__ ei, const unsigned short* __restrict__ x,
    int* __restrict__ flags, int* __restrict__ cnt1, int n1,
    int* __restrict__ cnt2, int n2) {
  int t = threadIdx.x;
  int g = blockIdx.x * 256 + t;
  int stride = gridDim.x * 256;
  for (int i = g; i < n1; i += stride) cnt1[i] = 0;
  for (int i = g; i < n2; i += stride) cnt2[i] = 0;
  if (blockIdx.x == 0) {
    __shared__ int red[256];
    int o = 0, big = 0;
    for (int i = t; i < 2048; i += 256) {
      o |= ei[2 * i + 1];
      float v = __uint_as_float(((unsigned)x[2 * i]) << 16);
      if (!(fabsf(v) < 1000.f)) big = 1;
    }
    red[t] = o;
    __syncthreads();
    for (int d = 128; d > 0; d >>= 1) {
      if (t < d) red[t] |= red[t + d];
      __syncthreads();
    }
    int o_all = red[0];
    __syncthreads();
    red[t] = big;
    __syncthreads();
    for (int d = 128; d > 0; d >>= 1) {
      if (t < d) red[t] |= red[t + d];
      __syncthreads();
    }
    if (t == 0) {
      flags[0] = red[0];
      flags[1] = (o_all == 0) ? 1 : 0;
    }
  }
}

__device__ __forceinline__ int edge_src(const int* ei, int E, int e, int i64) {
  return i64 ? ei[2 * e] : ei[e];
}
__device__ __forceinline__ int edge_dst(const int* ei, int E, int e, int i64) {
  return i64 ? ei[2 * E + 2 * e] : ei[E + e];
}

// ---------------------------------------------------------------------------
// node transform: 4 nodes per wave; W/bias/vj in registers.
// ea[n][h] = exp(h . v_j[h]) stored as bf16x8 via 10-shuffle butterfly.
// ---------------------------------------------------------------------------
template <int FIN>
__device__ __forceinline__ void node_body4(
    const void* x, const void* W, const void* b, int is_f32,
    const float* vj, bf16* h_out, unsigned short* ea_out, int n0, int N) {
  int lane = threadIdx.x & 63;
  float wreg[FIN];
#pragma unroll
  for (int f = 0; f < FIN; ++f) wreg[f] = loadf(W, lane * FIN + f, is_f32);
  float bias = loadf(b, lane, is_f32);
  float vjreg[8];
  if (ea_out) {
#pragma unroll
    for (int h = 0; h < 8; ++h) vjreg[h] = vj[h * 64 + lane];
  }
#pragma unroll
  for (int j = 0; j < 4; ++j) {
    int n = n0 + j;
    if (n >= N) break;  // wave-uniform
    float acc = bias;
#pragma unroll
    for (int f = 0; f < FIN; ++f)
      acc += loadf(x, n * FIN + f, is_f32) * wreg[f];
    float hv = acc > 0.f ? acc : expm1f(acc);
    h_out[(unsigned)(n << 6) + lane] = __float2bfloat16(hv);
    if (ea_out) {
      float p[8];
#pragma unroll
      for (int h = 0; h < 8; ++h) p[h] = hv * vjreg[h];
#pragma unroll
      for (int i = 0; i < 4; ++i) {
        float send = (lane & 4) ? p[i] : p[i + 4];
        float keep = (lane & 4) ? p[i + 4] : p[i];
        p[i] = keep + __shfl_xor(send, 4, 64);
      }
#pragma unroll
      for (int i = 0; i < 2; ++i) {
        float send = (lane & 2) ? p[i] : p[i + 2];
        float keep = (lane & 2) ? p[i + 2] : p[i];
        p[i] = keep + __shfl_xor(send, 2, 64);
      }
      {
        float send = (lane & 1) ? p[0] : p[1];
        float keep = (lane & 1) ? p[1] : p[0];
        p[0] = keep + __shfl_xor(send, 1, 64);
      }
      p[0] += __shfl_xor(p[0], 8, 64);
      p[0] += __shfl_xor(p[0], 16, 64);
      p[0] += __shfl_xor(p[0], 32, 64);
      if (lane < 8) ea_out[(unsigned)(n << 3) + lane] = f2bf(__expf(p[0]));
    }
  }
}

// ---------------------------------------------------------------------------
// front: node(op) | node(mc) | prep(weights) | count(edges) in ONE launch
// ---------------------------------------------------------------------------
__global__ __launch_bounds__(256) void front_kernel(
    const void* __restrict__ x_op, const void* __restrict__ W_op,
    const void* __restrict__ b_op, const void* __restrict__ x_mc,
    const void* __restrict__ W_mc, const void* __restrict__ b_mc,
    const void* __restrict__ W1, const void* __restrict__ att1,
    const void* __restrict__ W2, const void* __restrict__ att2,
    const int* __restrict__ ei, const int* __restrict__ flags,
    float* __restrict__ vj1, bf16* __restrict__ Wrt1, float* __restrict__ vj2,
    bf16* __restrict__ Wrt2, bf16* __restrict__ h_op,
    unsigned short* __restrict__ ea_op, bf16* __restrict__ h_mc,
    int* __restrict__ cnt_dst, int* __restrict__ cnt_src, int n_op, int n_mc,
    int E, int nbo, int nbm) {
  int bid = blockIdx.x;
  int is_f32 = flags[0];
  if (bid < nbo) {
    int n0 = bid * 16 + (threadIdx.x >> 6) * 4;
    if (n0 < n_op)
      node_body4<4>(x_op, W_op, b_op, is_f32, vj1, h_op, ea_op, n0, n_op);
  } else if (bid < nbo + nbm) {
    int n0 = (bid - nbo) * 16 + (threadIdx.x >> 6) * 4;
    if (n0 < n_mc)
      node_body4<2>(x_mc, W_mc, b_mc, is_f32, nullptr, h_mc, nullptr, n0, n_mc);
  } else if (bid < nbo + nbm + 256) {
    int pb = bid - nbo - nbm;
    int side = pb >= 128;
    const void* W = side ? W2 : W1;
    const void* att = side ? att2 : att1;
    float* vj = side ? vj2 : vj1;
    bf16* Wrt = side ? Wrt2 : Wrt1;
    int tt = (pb & 127) * 256 + threadIdx.x;
    if (tt < 32768) {
      int c = tt >> 9, k = tt & 511;
      int f = k >> 3, h = k & 7;
      Wrt[tt] = __float2bfloat16(loadf(W, ((h << 6) + c) * 64 + f, is_f32));
    }
    if (tt < 512) {
      int hh = tt >> 6, ff = tt & 63;
      float s = 0.f;
      for (int cc = 0; cc < 64; ++cc)
        s += loadf(att, hh * 128 + 64 + cc, is_f32) *
             loadf(W, ((hh << 6) + cc) * 64 + ff, is_f32);
      vj[tt] = s;
    }
  } else {
    int i64 = flags[1];
    int e = (bid - nbo - nbm - 256) * 256 + threadIdx.x;
    if (e < E) {
      atomicAdd(&cnt_dst[edge_dst(ei, E, e, i64)], 1);
      atomicAdd(&cnt_src[edge_src(ei, E, e, i64)], 1);
    }
  }
}

// ---------------------------------------------------------------------------
// CSR scan (2 kernels) + fill
// ---------------------------------------------------------------------------
__global__ __launch_bounds__(256) void scan_bsum2(
    const int* __restrict__ cnt1, int n1, int nb1, const int* __restrict__ cnt2,
    int n2, int* __restrict__ bsum1, int* __restrict__ bsum2) {
  __shared__ int red[256];
  int t = threadIdx.x;
  int side = (int)blockIdx.x >= nb1;
  const int* cnt = side ? cnt2 : cnt1;
  int n = side ? n2 : n1;
  int blk = side ? (blockIdx.x - nb1) : blockIdx.x;
  int base = blk * 2048 + t * 8;
  int s = 0;
#pragma unroll
  for (int i = 0; i < 8; ++i)
    if (base + i < n) s += cnt[base + i];
  red[t] = s;
  __syncthreads();
  for (int d = 128; d > 0; d >>= 1) {
    if (t < d) red[t] += red[t + d];
    __syncthreads();
  }
  if (t == 0) (side ? bsum2 : bsum1)[blk] = red[0];
}

__global__ __launch_bounds__(256) void scan_write2(
    const int* __restrict__ cnt1, int n1, int nb1,
    const int* __restrict__ bsum1, int* __restrict__ offs1,
    int* __restrict__ cur1, const int* __restrict__ cnt2, int n2, int nb2,
    const int* __restrict__ bsum2, int* __restrict__ offs2,
    int* __restrict__ cur2) {
  __shared__ int red[256];
  __shared__ int base_s;
  int t = threadIdx.x;
  int side = (int)blockIdx.x >= nb1;
  const int* cnt = side ? cnt2 : cnt1;
  const int* bsum = side ? bsum2 : bsum1;
  int* offs = side ? offs2 : offs1;
  int* cur = side ? cur2 : cur1;
  int n = side ? n2 : n1;
  int nb = side ? nb2 : nb1;
  int blk = side ? (blockIdx.x - nb1) : blockIdx.x;
  if (t == 0) {
    int b = 0;
    for (int i = 0; i < blk; ++i) b += bsum[i];
    base_s = b;
  }
  int base = blk * 2048 + t * 8;
  int c[8];
  int s = 0;
#pragma unroll
  for (int i = 0; i < 8; ++i) {
    c[i] = (base + i < n) ? cnt[base + i] : 0;
    s += c[i];
  }
  red[t] = s;
  __syncthreads();
  for (int d = 1; d < 256; d <<= 1) {
    int v = red[t];
    int add = (t >= d) ? red[t - d] : 0;
    __syncthreads();
    red[t] = v + add;
    __syncthreads();
  }
  int run = base_s + red[t] - s;
#pragma unroll
  for (int i = 0; i < 8; ++i) {
    if (base + i < n) {
      offs[base + i] = run;
      cur[base + i] = run;
      run += c[i];
    }
  }
  if (blk == nb - 1 && t == 255) offs[n] = base_s + red[255];
}

__global__ __launch_bounds__(256) void fill_edges(
    const int* __restrict__ ei, int E, const int* __restrict__ flags,
    int* __restrict__ cur1, int* __restrict__ srcs1, int* __restrict__ cur2,
    int* __restrict__ srcs2) {
  int i64 = flags[1];
  int e = blockIdx.x * blockDim.x + threadIdx.x;
  if (e < E) {
    int s = edge_src(ei, E, e, i64), d = edge_dst(ei, E, e, i64);
    int p = atomicAdd(&cur1[d], 1);
    srcs1[p] = s;
    int q = atomicAdd(&cur2[s], 1);
    srcs2[q] = d;
  }
}

// ---------------------------------------------------------------------------
// fused GAT v7 (R12 best): ZERO-STAGING gather. 16 dsts/block, 4 dsts/wave,
// quarter-wave streams. Per round each quarter reads srcs / h_src-rowslice /
// ea(bf16x8) DIRECTLY from global (L2-hot), quad-batched for 12 loads in
// flight. No LDS except Zl (MFMA staging) + ajp. Statless softmax (ea
// pre-exp'd), 1/s folded into the bf16 pack. MFMA epilogue 16x512 @ 512x64.
// ---------------------------------------------------------------------------
template <bool WRITE_AJ, bool WRITE_BF>
__global__ __launch_bounds__(256) void gat_fused(
    int Nd, const int* __restrict__ offs, const int* __restrict__ srcs,
    const unsigned short* __restrict__ ea, const bf16* __restrict__ h_src,
    const bf16* __restrict__ Wrt, const bf16* __restrict__ h_res,
    float* __restrict__ out_f32, bf16* __restrict__ out_bf,
    const float* __restrict__ vj_next, unsigned short* __restrict__ ea_next) {
  __shared__ __align__(16) unsigned short Zl[16 * 520];  // 16.3 KB
  __shared__ float ajp[4][16][8];                        // 2 KB

  int t = threadIdx.x;
  int wv = t >> 6, lane = t & 63;
  int d0 = blockIdx.x * 16;
  int sj = lane >> 4;  // dst slot within wave
  int fq = lane & 15;  // feature quad

  int dlo = d0 + wv * 4;
  int wo0 = offs[min(dlo + 0, Nd)];
  int wo1 = offs[min(dlo + 1, Nd)];
  int wo2 = offs[min(dlo + 2, Nd)];
  int wo3 = offs[min(dlo + 3, Nd)];
  int wo4 = offs[min(dlo + 4, Nd)];
  int woj = sj == 0 ? wo0 : sj == 1 ? wo1 : sj == 2 ? wo2 : wo3;
  int woj1 = sj == 0 ? wo1 : sj == 1 ? wo2 : sj == 2 ? wo3 : wo4;
  int nj = woj1 - woj;

  float z[8][4];
#pragma unroll
  for (int h = 0; h < 8; ++h)
#pragma unroll
    for (int f = 0; f < 4; ++f) z[h][f] = 0.f;
  float s8[8];
#pragma unroll
  for (int h = 0; h < 8; ++h) s8[h] = 0.f;

  const unsigned short* hsrc_u = (const unsigned short*)h_src;

  int rmax = max(nj, __shfl_xor(nj, 16, 64));
  rmax = max(rmax, __shfl_xor(rmax, 32, 64));

  for (int r0 = 0; r0 < rmax; r0 += 4) {
    unsigned srcq[4];
#pragma unroll
    for (int q = 0; q < 4; ++q) {
      int r = r0 + q;
      srcq[q] = (r < nj) ? (unsigned)srcs[woj + r] : 0u;
    }
    ushort4 uq[4];
    short8 eq[4];
#pragma unroll
    for (int q = 0; q < 4; ++q) {
      unsigned s = srcq[q];
      uq[q] = *(const ushort4*)(hsrc_u + (s << 6) + (fq << 2));
      eq[q] = *(const short8*)(ea + (s << 3));
    }
#pragma unroll
    for (int q = 0; q < 4; ++q) {
      bool act = (r0 + q) < nj;
      float w[8];
#pragma unroll
      for (int h = 0; h < 8; ++h)
        w[h] = act ? bf2f((unsigned short)eq[q][h]) : 0.f;
      float x0 = bf2f(uq[q].x), x1 = bf2f(uq[q].y);
      float x2 = bf2f(uq[q].z), x3 = bf2f(uq[q].w);
#pragma unroll
      for (int h = 0; h < 8; ++h) {
        z[h][0] += w[h] * x0;
        z[h][1] += w[h] * x1;
        z[h][2] += w[h] * x2;
        z[h][3] += w[h] * x3;
        s8[h] += w[h];
      }
    }
  }

  // normalize at pack time -> Zl bf16, row = wv*4+sj, k' = (fq*4+fi)*8 + h
  float si[8];
#pragma unroll
  for (int h = 0; h < 8; ++h) si[h] = s8[h] > 0.f ? 1.f / s8[h] : 0.f;
  int row = wv * 4 + sj;
#pragma unroll
  for (int fi = 0; fi < 4; ++fi) {
    int4 pk;
    pk.x = ((int)f2bf(z[1][fi] * si[1]) << 16) | f2bf(z[0][fi] * si[0]);
    pk.y = ((int)f2bf(z[3][fi] * si[3]) << 16) | f2bf(z[2][fi] * si[2]);
    pk.z = ((int)f2bf(z[5][fi] * si[5]) << 16) | f2bf(z[4][fi] * si[4]);
    pk.w = ((int)f2bf(z[7][fi] * si[7]) << 16) | f2bf(z[6][fi] * si[6]);
    *(int4*)&Zl[row * 520 + (fq * 4 + fi) * 8] = pk;
  }

  // prefetch residual (independent of Zl) before the barrier
  int arow = lane & 15;
  int kg = lane >> 4;
  int col = wv * 16 + arow;
  float res[4];
#pragma unroll
  for (int r = 0; r < 4; ++r) {
    int d = d0 + kg * 4 + r;
    res[r] =
        (d < Nd) ? __bfloat162float(h_res[(unsigned)(d << 6) + col]) : 0.f;
  }
  __syncthreads();

  // MFMA epilogue: wave wv computes rows 0..15, cols wv*16..wv*16+15
  f32x4 acc = {0.f, 0.f, 0.f, 0.f};
#pragma unroll
  for (int kt = 0; kt < 16; ++kt) {
    int kbase = kt * 32 + kg * 8;
    short8 a = *(const short8*)&Zl[arow * 520 + kbase];
    short8 b = *(const short8*)&Wrt[(unsigned)((wv * 16 + arow) * 512 + kbase)];
    acc = __builtin_amdgcn_mfma_f32_16x16x32_bf16(a, b, acc, 0, 0, 0);
  }

  float o_r[4];
#pragma unroll
  for (int r = 0; r < 4; ++r) {
    int d = d0 + kg * 4 + r;
    float o = 0.f;
    if (d < Nd) {
      float v = res[r] + 0.125f * acc[r];
      o = v > 0.f ? v : expm1f(v);
      out_f32[(unsigned)(d << 6) + col] = o;
      if (WRITE_BF) out_bf[(unsigned)(d << 6) + col] = __float2bfloat16(o);
    }
    o_r[r] = o;
  }

  if (WRITE_AJ) {
#pragma unroll
    for (int r = 0; r < 4; ++r) {
      int dloc = kg * 4 + r;
      float p[8];
#pragma unroll
      for (int h = 0; h < 8; ++h) p[h] = o_r[r] * vj_next[h * 64 + col];
#pragma unroll
      for (int i = 0; i < 4; ++i) {
        float send = (arow & 4) ? p[i] : p[i + 4];
        float keep = (arow & 4) ? p[i + 4] : p[i];
        p[i] = keep + __shfl_xor(send, 4, 64);
      }
#pragma unroll
      for (int i = 0; i < 2; ++i) {
        float send = (arow & 2) ? p[i] : p[i + 2];
        float keep = (arow & 2) ? p[i + 2] : p[i];
        p[i] = keep + __shfl_xor(send, 2, 64);
      }
      {
        float send = (arow & 1) ? p[0] : p[1];
        float keep = (arow & 1) ? p[1] : p[0];
        p[0] = keep + __shfl_xor(send, 1, 64);
      }
      p[0] += __shfl_xor(p[0], 8, 64);
      if (arow < 8) ajp[wv][dloc][arow] = p[0];
    }
    __syncthreads();
    if (t < 128) {
      int dloc = t >> 3, h = t & 7;
      int d = d0 + dloc;
      if (d < Nd) {
        float s = ajp[0][dloc][h] + ajp[1][dloc][h] + ajp[2][dloc][h] +
                  ajp[3][dloc][h];
        ea_next[(unsigned)(d << 3) + h] = f2bf(__expf(s));
      }
    }
  }
}

// ---------------------------------------------------------------------------
extern "C" void kernel_launch(void* const* d_in, const int* in_sizes, int n_in,
                              void* d_out, int out_size, void* d_ws,
                              size_t ws_size, hipStream_t stream) {
  const void* op_nodes = d_in[0];
  const void* mc_nodes = d_in[1];
  const int* ei        = (const int*)d_in[2];
  const void* W_op     = d_in[3];
  const void* b_op     = d_in[4];
  const void* W_mc     = d_in[5];
  const void* b_mc     = d_in[6];
  const void* W_om     = d_in[7];
  const void* att_om   = d_in[8];
  const void* W_mo     = d_in[9];
  const void* att_mo   = d_in[10];

  int n_op = in_sizes[0] / 4;
  int n_mc = in_sizes[1] / 2;
  int E    = in_sizes[2] / 2;

  char* ws = (char*)d_ws;
  size_t off = 0;
  auto alloc = [&](size_t bytes) -> void* {
    void* p = ws + off;
    off = (off + bytes + 255) & ~(size_t)255;
    return p;
  };
  int* flags   = (int*)alloc(16);
  bf16* h_op   = (bf16*)alloc((size_t)n_op * 64 * 2);
  bf16* h_mc   = (bf16*)alloc((size_t)n_mc * 64 * 2);
  bf16* h_mc2  = (bf16*)alloc((size_t)n_mc * 64 * 2);
  unsigned short* ea_op = (unsigned short*)alloc((size_t)n_op * 8 * 2);
  unsigned short* ea_mc = (unsigned short*)alloc((size_t)n_mc * 8 * 2);
  float* vj_om = (float*)alloc(512 * 4);
  float* vj_mo = (float*)alloc(512 * 4);
  bf16* Wrt_om = (bf16*)alloc(32768 * 2);
  bf16* Wrt_mo = (bf16*)alloc(32768 * 2);
  int* cnt1  = (int*)alloc((size_t)n_mc * 4);
  int* cnt2  = (int*)alloc((size_t)n_op * 4);
  int* offs1 = (int*)alloc((size_t)(n_mc + 1) * 4);
  int* cur1  = (int*)alloc((size_t)n_mc * 4);
  int* srcs1 = (int*)alloc((size_t)E * 4);
  int* offs2 = (int*)alloc((size_t)(n_op + 1) * 4);
  int* cur2  = (int*)alloc((size_t)n_op * 4);
  int* srcs2 = (int*)alloc((size_t)E * 4);
  int* bsum1 = (int*)alloc(256 * 4);
  int* bsum2 = (int*)alloc(256 * 4);

  float* out_op = (float*)d_out;
  float* out_mc = out_op + (size_t)n_op * 64;

  init_kernel<<<512, 256, 0, stream>>>(ei, (const unsigned short*)op_nodes,
                                       flags, cnt1, n_mc, cnt2, n_op);

  int nbo = (n_op + 15) / 16, nbm = (n_mc + 15) / 16;
  int nbe = (E + 255) / 256;
  front_kernel<<<nbo + nbm + 256 + nbe, 256, 0, stream>>>(
      op_nodes, W_op, b_op, mc_nodes, W_mc, b_mc, W_om, att_om, W_mo, att_mo,
      ei, flags, vj_om, Wrt_om, vj_mo, Wrt_mo, h_op, ea_op, h_mc, cnt1, cnt2,
      n_op, n_mc, E, nbo, nbm);

  int nb1 = (n_mc + 2047) / 2048, nb2 = (n_op + 2047) / 2048;
  scan_bsum2<<<nb1 + nb2, 256, 0, stream>>>(cnt1, n_mc, nb1, cnt2, n_op, bsum1,
                                            bsum2);
  scan_write2<<<nb1 + nb2, 256, 0, stream>>>(cnt1, n_mc, nb1, bsum1, offs1,
                                             cur1, cnt2, n_op, nb2, bsum2,
                                             offs2, cur2);
  fill_edges<<<nbe, 256, 0, stream>>>(ei, E, flags, cur1, srcs1, cur2, srcs2);

  // GAT1: op -> mc (writes out_mc f32 + h_mc2 bf16 + ea_mc)
  gat_fused<true, true><<<(n_mc + 15) / 16, 256, 0, stream>>>(
      n_mc, offs1, srcs1, ea_op, h_op, Wrt_om, h_mc, out_mc, h_mc2, vj_mo,
      ea_mc);
  // GAT2: mc -> op (src = h_mc2 bf16)
  gat_fused<false, false><<<(n_op + 15) / 16, 256, 0, stream>>>(
      n_op, offs2, srcs2, ea_mc, h_mc2, Wrt_mo, h_op, out_op, (bf16*)nullptr,
      (const float*)nullptr, (unsigned short*)nullptr);
}